// Round 5
// baseline (974.987 us; speedup 1.0000x reference)
//
#include <hip/hip_runtime.h>
#include <math.h>

#define B 512
#define D 1024
#define H 512
#define C 48
#define K 3
#define T 25
#define DP1 1025
#define G4H 2048
#define NC 2112         // step GEMM N (padded): 2048 gates | 48 logits | 16 pad
#define NCV 2096        // valid cols
#define KP 1056         // padded K for x0/embed rows (multiple of 32)
#define FK 6304         // padded feat-K (6288 -> 6304)

typedef _Float16 f16;
typedef _Float16 half8 __attribute__((ext_vector_type(8)));
typedef float floatx4 __attribute__((ext_vector_type(4)));

__device__ __forceinline__ float sigf(float x){ return 1.0f/(1.0f+expf(-x)); }

// ================= split-f16 MFMA GEMM: 64x64 tile, BK=32, 4 waves =================
// Double-buffered LDS (1 barrier per K-step), XCD swizzle (n-chunked or z-major), split-K via Z.

template<int MODE>
__device__ __forceinline__ void mf_load(
    const f16* __restrict__ Ahi, const f16* __restrict__ Alo,
    const f16* __restrict__ Bhi, const f16* __restrict__ Blo,
    int M, int lda, int ldb, int m0, int n0, int kbase, int k0, int t,
    const f16* __restrict__ Yh, const f16* __restrict__ Yl,
    const float* __restrict__ Sf, const float* __restrict__ Rf,
    half8& rah, half8& ral, half8& rbh, half8& rbl)
{
    int r = t>>2, seg = t&3;
    int kk = k0 + seg*8;
    {
        size_t off = (size_t)(n0+r)*ldb + kbase + kk;
        rbh = *(const half8*)(Bhi + off);
        rbl = *(const half8*)(Blo + off);
    }
    int m = m0 + r;
    if (MODE==0){
        if (m < M){
            size_t off = (size_t)m*lda + kbase + kk;
            rah = *(const half8*)(Ahi + off);
            ral = *(const half8*)(Alo + off);
        } else {
            #pragma unroll
            for (int i=0;i<8;i++){ rah[i]=(f16)0; ral[i]=(f16)0; }
        }
    } else {
        int kabs = kbase + kk;   // 8-aligned; source runs never straddle boundaries
        if (kabs < 144){
            rah = *(const half8*)(Yh + (size_t)m*144 + kabs);
            ral = *(const half8*)(Yl + (size_t)m*144 + kabs);
        } else if (kabs < 6288){
            int kp = kabs - 144;
            const float* src = (kp < 3*D)
                ? (Sf + (size_t)(kp>>10)*(B*D) + (size_t)m*D + (kp&(D-1)))
                : (Rf + (size_t)((kp-3*D)>>10)*(B*D) + (size_t)m*D + ((kp-3*D)&(D-1)));
            float4 f0 = *(const float4*)src;
            float4 f1 = *(const float4*)(src+4);
            float fv[8]={f0.x,f0.y,f0.z,f0.w,f1.x,f1.y,f1.z,f1.w};
            #pragma unroll
            for (int i=0;i<8;i++){
                f16 h=(f16)fv[i];
                rah[i]=h; ral[i]=(f16)(fv[i]-(float)h);
            }
        } else {
            #pragma unroll
            for (int i=0;i<8;i++){ rah[i]=(f16)0; ral[i]=(f16)0; }
        }
    }
}

template<int MODE>
__global__ __launch_bounds__(256)
void k_mfma(const f16* __restrict__ Ahi, const f16* __restrict__ Alo,
            const f16* __restrict__ Bhi, const f16* __restrict__ Blo,
            float* __restrict__ Cc, const float* __restrict__ bias,
            int M, int Nvalid, int Ktot, int lda, int ldb, int ldc,
            int ksl, size_t cstride, int MB, int Z, int zmaj,
            const f16* __restrict__ Yh, const f16* __restrict__ Yl,
            const float* __restrict__ Sf, const float* __restrict__ Rf)
{
    __shared__ __align__(16) f16 Ash[2][64][40];
    __shared__ __align__(16) f16 Asl[2][64][40];
    __shared__ __align__(16) f16 Bsh[2][64][40];
    __shared__ __align__(16) f16 Bsl[2][64][40];
    int t = threadIdx.x;
    int mblk, nblk, z;
    if (zmaj){
        // z-major: XCD (round-robin by blockIdx) owns a K-slice -> B-slice stays in its L2
        z = blockIdx.x % Z;
        int rest = blockIdx.x / Z;
        mblk = rest % MB; nblk = rest / MB;
    } else {
        // n-chunked: same-XCD blocks share an n-range (B-panel reuse across mblks)
        int chunk = gridDim.x >> 3;
        int g = (blockIdx.x & 7)*chunk + (blockIdx.x >> 3);
        int mz = g % (MB*Z);
        nblk = g / (MB*Z);
        mblk = mz / Z;
        z    = mz % Z;
    }
    int m0 = mblk*64, n0 = nblk*64;
    int kbase = z*ksl;
    int kcnt = (z==Z-1)? (Ktot-kbase) : ksl;
    int nIter = kcnt >> 5;
    int r = t>>2, seg = t&3;
    half8 rah, ral, rbh, rbl;
    mf_load<MODE>(Ahi,Alo,Bhi,Blo,M,lda,ldb,m0,n0,kbase,0,t,Yh,Yl,Sf,Rf,rah,ral,rbh,rbl);
    int lane = t&63, wv = t>>6;
    int lrow = lane&15, quad = lane>>4;
    floatx4 acc[4] = {};
    int cur = 0;
    for (int it=0; it<nIter; ++it){
        *(half8*)&Ash[cur][r][seg*8] = rah;
        *(half8*)&Asl[cur][r][seg*8] = ral;
        *(half8*)&Bsh[cur][r][seg*8] = rbh;
        *(half8*)&Bsl[cur][r][seg*8] = rbl;
        if (it+1 < nIter)
            mf_load<MODE>(Ahi,Alo,Bhi,Blo,M,lda,ldb,m0,n0,kbase,(it+1)<<5,t,Yh,Yl,Sf,Rf,rah,ral,rbh,rbl);
        __syncthreads();
        half8 ah = *(const half8*)&Ash[cur][wv*16+lrow][quad*8];
        half8 al = *(const half8*)&Asl[cur][wv*16+lrow][quad*8];
        #pragma unroll
        for (int j=0;j<4;j++){
            half8 bh = *(const half8*)&Bsh[cur][j*16+lrow][quad*8];
            half8 bl = *(const half8*)&Bsl[cur][j*16+lrow][quad*8];
            acc[j] = __builtin_amdgcn_mfma_f32_16x16x32_f16(ah, bh, acc[j], 0,0,0);
            acc[j] = __builtin_amdgcn_mfma_f32_16x16x32_f16(al, bh, acc[j], 0,0,0);
            acc[j] = __builtin_amdgcn_mfma_f32_16x16x32_f16(ah, bl, acc[j], 0,0,0);
        }
        cur ^= 1;
    }
    float* Cz = Cc + (size_t)z*cstride;
    #pragma unroll
    for (int j=0;j<4;j++){
        int col = n0 + j*16 + lrow;
        if (col >= Nvalid) continue;
        float bv = bias ? bias[col] : 0.f;
        #pragma unroll
        for (int i=0;i<4;i++){
            int row = m0 + wv*16 + quad*4 + i;
            if (row < M) Cz[(size_t)row*ldc + col] = acc[j][i] + bv;
        }
    }
}

// ================= setup kernels =================

__global__ void k_bt_build(const float* __restrict__ src, f16* __restrict__ hi, f16* __restrict__ lo,
                           int Ksrc, int Nsrc, int ld_src, int NB, int KB, float scale){
    __shared__ float tile[32][33];
    int k0 = blockIdx.x*32, n0 = blockIdx.y*32;
    int lx = threadIdx.x & 31, ly = threadIdx.x >> 5;
    for (int rr=0; rr<32; rr+=8){
        int k2 = k0+ly+rr, n = n0+lx;
        tile[ly+rr][lx] = (k2<Ksrc && n<Nsrc)? src[(size_t)k2*ld_src+n]*scale : 0.f;
    }
    __syncthreads();
    for (int rr=0; rr<32; rr+=8){
        int n = n0+ly+rr, k2 = k0+lx;
        if (n<NB && k2<KB){
            float v = tile[lx][ly+rr];
            f16 h=(f16)v;
            hi[(size_t)n*KB+k2]=h;
            lo[(size_t)n*KB+k2]=(f16)(v-(float)h);
        }
    }
}

__global__ void k_permrows(const float* __restrict__ src, f16* __restrict__ hi, f16* __restrict__ lo,
                           int src_ld, int dst_ld, int kvalid){
    int idx = blockIdx.x*256+threadIdx.x;
    if (idx >= G4H*dst_ld) return;
    int p = idx/dst_ld, k2 = idx%dst_ld;
    int j = p>>2, g = p&3, gi = (g<<9)|j;
    float v = (k2<kvalid)? src[(size_t)gi*src_ld + k2] : 0.f;
    f16 h=(f16)v;
    hi[idx]=h; lo[idx]=(f16)(v-(float)h);
}

__global__ void k_cvt(const float* __restrict__ src, f16* __restrict__ hi, f16* __restrict__ lo,
                      int M, int ld_src, int nvalid, int ld_dst, float scale){
    int idx = blockIdx.x*256+threadIdx.x;
    if (idx >= M*ld_dst) return;
    int m = idx/ld_dst, n = idx%ld_dst;
    float v = (n<nvalid)? src[(size_t)m*ld_src+n]*scale : 0.f;
    f16 h=(f16)v; hi[idx]=h; lo[idx]=(f16)(v-(float)h);
}

__global__ void k_cvtY(const float* __restrict__ Y, f16* __restrict__ hi, f16* __restrict__ lo){
    int idx = blockIdx.x*256+threadIdx.x;
    if (idx >= B*144) return;
    int b = idx/144, k2 = idx%144;
    float v = Y[((size_t)(k2/C)*B + b)*C + (k2%C)];
    f16 h=(f16)v; hi[idx]=h; lo[idx]=(f16)(v-(float)h);
}

__global__ void k_zeroh(f16* a, f16* b2, int n){
    int i = blockIdx.x*256+threadIdx.x; if (i<n){ a[i]=(f16)0; b2[i]=(f16)0; }
}

__global__ void k_prep(const float* __restrict__ bih, const float* __restrict__ bhh,
                       const float* __restrict__ bp, const float* __restrict__ Wih,
                       float* __restrict__ bias2p, float* __restrict__ biascat,
                       float* __restrict__ wl){
    int i = blockIdx.x*256 + threadIdx.x;
    if (i < G4H){
        int g=i&3, j=i>>2; int gi=(g<<9)|j;
        bias2p[i]=bih[gi]+bhh[gi];
        wl[i]=Wih[(size_t)gi*DP1 + 1024];
    }
    if (i < C) biascat[i]=bp[i];
}

__global__ void k_cls(const float* __restrict__ S, const float* __restrict__ R,
                      const float* __restrict__ clsW, const float* __restrict__ clsb,
                      float* __restrict__ Y){
    int kb = blockIdx.x; int k = kb / B; int b = kb % B;
    int t = threadIdx.x; // 64
    __shared__ float sr[64];
    __shared__ float lg[C];
    __shared__ float mred[2];
    float acc = (t<C) ? clsb[k*C+t] : 0.f;
    const float* W = clsW + (size_t)k*2*D*C;
    for (int i0=0; i0<2*D; i0+=64){
        int i = i0 + t;
        sr[t] = (i < D) ? S[((size_t)k*B+b)*D + i] : R[((size_t)k*B+b)*D + (i-D)];
        __syncthreads();
        if (t < C){ for (int ii=0; ii<64; ++ii) acc += sr[ii]*W[(size_t)(i0+ii)*C + t]; }
        __syncthreads();
    }
    if (t<C) lg[t]=acc;
    __syncthreads();
    if (t==0){
        float m=lg[0]; for(int c2=1;c2<C;c2++) m=fmaxf(m,lg[c2]);
        float s=0.f; for(int c2=0;c2<C;c2++) s+=expf(lg[c2]-m);
        mred[0]=m; mred[1]=s;
    }
    __syncthreads();
    if (t<C) Y[((size_t)k*B+b)*C + t] = expf(lg[t]-mred[0])/mred[1];
}

__global__ void k_curr_action(const float* __restrict__ Y, float* __restrict__ outca){
    int i = blockIdx.x*256+threadIdx.x; if (i>=B*C) return;
    int b=i/C, c2=i%C;
    outca[i] = Y[((size_t)0*B+b)*C+c2] + Y[((size_t)1*B+b)*C+c2] + Y[((size_t)2*B+b)*C+c2];
}

__global__ void k_dur0(const float* __restrict__ R, const float* __restrict__ durW,
                       const float* __restrict__ durb, float* __restrict__ outpad){
    int b = blockIdx.x; int t = threadIdx.x;
    __shared__ float red[256];
    float p=0.f;
    for (int i=t; i<K*D; i+=256){ int k=i>>10, d=i&1023; p += R[((size_t)k*B+b)*D+d]*durW[i]; }
    red[t]=p; __syncthreads();
    for (int s=128;s>0;s>>=1){ if(t<s) red[t]+=red[t+s]; __syncthreads(); }
    if (t==0) outpad[(size_t)b*(T+1)] = red[0] + durb[0];
}

__global__ void k_red(float* __restrict__ dst, const float* __restrict__ src, int parts, size_t pstride,
                      int M, int Nld, int Nvalid, const float* __restrict__ bias){
    int idx = blockIdx.x*256+threadIdx.x;
    if (idx >= M*Nld) return;
    int n = idx % Nld;
    float v = 0.f;
    if (n < Nvalid){
        for (int p=0;p<parts;p++) v += src[(size_t)p*pstride + idx];
        if (bias) v += bias[n];
    }
    dst[idx]=v;
}

__global__ void k_redcvt(const float* __restrict__ src, int parts, size_t pstride,
                         const float* __restrict__ bias, f16* __restrict__ hi, f16* __restrict__ lo){
    int idx = blockIdx.x*256+threadIdx.x;
    if (idx >= 512*KP) return;
    int m = idx/KP, n = idx%KP;
    float v = 0.f;
    if (n < DP1){
        for (int p=0;p<parts;p++) v += src[(size_t)p*pstride + (size_t)m*1028 + n];
        v += bias[n];
    }
    f16 h=(f16)v; hi[idx]=h; lo[idx]=(f16)(v-(float)h);
}

// ================= scan kernels =================

// fused split-K reduce + bias + LSTM step 0
__global__ void k_lstm0(const float* __restrict__ gxp, int parts, size_t pstride,
                        const float* __restrict__ bias2p,
                        float* __restrict__ c, f16* __restrict__ hhi, f16* __restrict__ hlo){
    int idx = blockIdx.x*256+threadIdx.x; if (idx>=B*H) return;
    int r=idx>>9, j=idx&511;
    float4 g = *(const float4*)&gxp[(size_t)r*G4H + (j<<2)];
    if (parts==2){
        float4 g2 = *(const float4*)&gxp[pstride + (size_t)r*G4H + (j<<2)];
        g.x+=g2.x; g.y+=g2.y; g.z+=g2.z; g.w+=g2.w;
    }
    float4 bb = *(const float4*)&bias2p[j<<2];
    g.x+=bb.x; g.y+=bb.y; g.z+=bb.z; g.w+=bb.w;
    float cn = sigf(g.x)*tanhf(g.z);
    c[idx]=cn;
    float hv = sigf(g.w)*tanhf(cn);
    f16 h=(f16)hv; hhi[idx]=h; hlo[idx]=(f16)(hv-(float)h);
}

// fused: softmax/argmax + probs + attention (via precomputed V) + dur head + LSTM cell.
// 512 threads; wave-shfl reductions; PARTS-way split-K partial sum inline.
template<int PARTS>
__global__ void k_postapply(const float* __restrict__ rawg, size_t pstride,
                       const float* __restrict__ S, const float* __restrict__ V,
                       const f16* __restrict__ hchi, const f16* __restrict__ hclo,
                       const f16* __restrict__ holdhi, const f16* __restrict__ holdlo,
                       const float* __restrict__ E, const float* __restrict__ wl,
                       const float* __restrict__ biascat,
                       const float* __restrict__ Wdur, const float* __restrict__ bdur,
                       float* __restrict__ outlab, float* __restrict__ outprobs,
                       float* __restrict__ outatt, float* __restrict__ outpad,
                       float* __restrict__ c, f16* __restrict__ hNhi, f16* __restrict__ hNlo,
                       int tstep, int doLstm)
{
    int b=blockIdx.x, t=threadIdx.x;
    int lane=t&63, wv=t>>6;
    __shared__ float aw[3];
    __shared__ float redw[4][8];
    __shared__ int sbest;
    __shared__ float sdv;
    const float* z0 = rawg + (size_t)b*NC;
    // logits softmax/argmax on wave 0
    if (t<64){
        float lgv = -3.0e38f;
        if (t<C){
            float v = 0.f;
            #pragma unroll
            for (int p=0;p<PARTS;p++) v += z0[(size_t)p*pstride + G4H + t];
            lgv = v + biascat[t];
        }
        float m = lgv; int bi = t;
        #pragma unroll
        for (int s2=32;s2>0;s2>>=1){
            float om=__shfl_xor(m,s2); int ob=__shfl_xor(bi,s2);
            if (om>m || (om==m && ob<bi)){ m=om; bi=ob; }
        }
        float e=(t<C)? expf(lgv-m):0.f;
        float ss=e;
        #pragma unroll
        for (int s2=32;s2>0;s2>>=1) ss+=__shfl_xor(ss,s2);
        if (t<C) outprobs[(size_t)b*(T*C)+tstep*C+t]=e/ss;
        if (t==0){
            sbest=bi;
            outlab[(size_t)tstep*B+b]=(float)bi;
        }
    }
    // attention scores via precomputed V: p_k = h . V[k,b,:]
    float hv_t = (float)hchi[(size_t)b*H + t] + (float)hclo[(size_t)b*H + t];
    float p0 = hv_t * V[((size_t)(0*B+b))*H + t];
    float p1 = hv_t * V[((size_t)(1*B+b))*H + t];
    float p2 = hv_t * V[((size_t)(2*B+b))*H + t];
    #pragma unroll
    for (int s2=32;s2>0;s2>>=1){
        p0 += __shfl_xor(p0,s2); p1 += __shfl_xor(p1,s2); p2 += __shfl_xor(p2,s2);
    }
    if (lane==0){ redw[0][wv]=p0; redw[1][wv]=p1; redw[2][wv]=p2; }
    __syncthreads();
    if (t==0){
        float a0=0.f,a1=0.f,a2=0.f;
        #pragma unroll
        for (int w=0;w<8;w++){ a0+=redw[0][w]; a1+=redw[1][w]; a2+=redw[2][w]; }
        float m=fmaxf(a0,fmaxf(a1,a2));
        float e0=expf(a0-m), e1=expf(a1-m), e2=expf(a2-m);
        float si=1.f/(e0+e1+e2);
        aw[0]=e0*si; aw[1]=e1*si; aw[2]=e2*si;
    }
    __syncthreads();
    float a0=aw[0],a1=aw[1],a2=aw[2];
    const float* S0  = S + (size_t)b*D;
    const float* S1  = S0 + (size_t)B*D;
    const float* S2p = S1 + (size_t)B*D;
    float dp = 0.f;
    float* attp = outatt + (size_t)tstep*B*D + (size_t)b*D;
    {
        int d = t<<1;   // single pass: 512 threads x float2 = 1024 floats = D
        float2 s0 = *(const float2*)(S0+d);
        float2 s1 = *(const float2*)(S1+d);
        float2 s2 = *(const float2*)(S2p+d);
        float2 w2 = *(const float2*)(Wdur+d);
        float2 av;
        av.x = a0*s0.x+a1*s1.x+a2*s2.x;
        av.y = a0*s0.y+a1*s1.y+a2*s2.y;
        *(float2*)(attp+d) = av;
        dp += av.x*w2.x+av.y*w2.y;
    }
    if (holdhi){
        float hvo = (float)holdhi[(size_t)b*H+t] + (float)holdlo[(size_t)b*H+t];
        dp += hvo * Wdur[D+t];
    }
    #pragma unroll
    for (int s2=32;s2>0;s2>>=1) dp += __shfl_xor(dp,s2);
    if (lane==0) redw[3][wv]=dp;
    __syncthreads();
    if (t==0){
        float dv=0.f;
        #pragma unroll
        for (int w=0;w<8;w++) dv+=redw[3][w];
        dv += bdur[0];
        outpad[(size_t)b*(T+1)+tstep+1]=dv; sdv=dv;
    }
    __syncthreads();
    if (doLstm){
        int lb=sbest; float dv=sdv;
        int j=t;   // 512 threads == H
        float4 g4 = *(const float4*)&z0[4*j];
        #pragma unroll
        for (int p=1;p<PARTS;p++){
            float4 h4 = *(const float4*)&z0[(size_t)p*pstride + 4*j];
            g4.x+=h4.x; g4.y+=h4.y; g4.z+=h4.z; g4.w+=h4.w;
        }
        float4 e4 = *(const float4*)&E[(size_t)lb*G4H+4*j];
        float4 w4 = *(const float4*)&wl[4*j];
        float gi = g4.x+e4.x+dv*w4.x;
        float gf = g4.y+e4.y+dv*w4.y;
        float gg = g4.z+e4.z+dv*w4.z;
        float go = g4.w+e4.w+dv*w4.w;
        size_t ci=(size_t)b*H+j;
        float cn = sigf(gf)*c[ci] + sigf(gi)*tanhf(gg);
        c[ci]=cn;
        float hv = sigf(go)*tanhf(cn);
        f16 hh=(f16)hv;
        hNhi[ci]=hh; hNlo[ci]=(f16)(hv-(float)hh);
    }
}

// ================= host =================

extern "C" void kernel_launch(void* const* d_in, const int* in_sizes, int n_in,
                              void* d_out, int out_size, void* d_ws, size_t ws_size,
                              hipStream_t stream) {
    const float* S    = (const float*)d_in[0];
    const float* R    = (const float*)d_in[1];
    const float* clsW = (const float*)d_in[2];
    const float* clsb = (const float*)d_in[3];
    const float* durW = (const float*)d_in[4];
    const float* durb = (const float*)d_in[5];
    const float* linW = (const float*)d_in[6];
    const float* linb = (const float*)d_in[7];
    const float* Wih  = (const float*)d_in[8];
    const float* Whh  = (const float*)d_in[9];
    const float* bih  = (const float*)d_in[10];
    const float* bhh  = (const float*)d_in[11];
    const float* Wp   = (const float*)d_in[12];
    const float* bp   = (const float*)d_in[13];
    const float* Wdur = (const float*)d_in[14];
    const float* bdur = (const float*)d_in[15];
    const float* embed= (const float*)d_in[16];
    const float* Wattn= (const float*)d_in[17];

    float* out = (float*)d_out;
    float* outlab   = out;                 // [T,B]
    float* outprobs = out + 12800;         // [B,T,C]
    float* outca    = out + 627200;        // [B,C]
    float* outpad   = out + 651776;        // [B,T+1]
    float* outatt   = out + 665088;        // [T,B,D]

    float* ws = (float*)d_ws;
    // persistent block
    float* E       = ws + 0;               // 98,304
    float* wl      = ws + 98304;           // 2,048
    float* bias2p  = ws + 100352;          // 2,048
    float* biascat = ws + 102400;          // 64
    float* c       = ws + 102464;          // 262,144
    f16*   hAhi    = (f16*)(ws + 364608);  // 262,144 f16
    f16*   hAlo    = (f16*)(ws + 495680);
    f16*   hBhi    = (f16*)(ws + 626752);
    f16*   hBlo    = (f16*)(ws + 757824);
    f16*   Yhi     = (f16*)(ws + 889920);  // 512*144 f16
    f16*   Ylo     = (f16*)(ws + 926784);
    float* Y       = ws + 963648;          // 73,728 -> ends 1,037,376
    f16*   watthi  = (f16*)(ws + 1037376); // 512*1024 f16 = 262,144 fl
    f16*   wattlo  = (f16*)(ws + 1299520); // ends 1,561,664 < 1,563,712
    f16*   x0hi    = (f16*)(ws + 1563712); // 512*1056 f16
    f16*   x0lo    = (f16*)(ws + 1834048);
    f16*   embhi   = (f16*)(ws + 2104384); // 48*1056 f16
    f16*   emblo   = (f16*)(ws + 2129728);
    // big scratch region, time-multiplexed:
    //  stage1 (x0): linWt hi/lo [SB .. SB+6,858,752) + x0part [SB+6,858,752 ..)
    //  stage2: Wct2 | S hi/lo | V | Wihp (setup) / rawg 4-parts (scan, overlays dead Wihp)
    //          gpart (gx0/E partials) after Wihp; all within the 40.26 MB floor.
    const size_t SB = 2155072;
    f16*   lwthi   = (f16*)(ws + SB);               // 1088*6304 f16
    f16*   lwtlo   = (f16*)(ws + SB + 3429376);
    float* x0part  = ws + SB + 6858752;             // ZX0*512*1028 (ws-gated)
    f16*   Wcthi   = (f16*)(ws + SB);               // 2112*512 f16 = 540,672 fl
    f16*   Wctlo   = (f16*)(ws + SB + 540672);      // ends SB+1,081,344
    f16*   Shi     = (f16*)(ws + SB + 1081344);     // 1536*1024 f16 = 786,432 fl
    f16*   Slo     = (f16*)(ws + SB + 1867776);     // ends SB+2,654,208
    float* Vbuf    = ws + SB + 2654208;             // 786,432 fl, ends SB+3,440,640
    f16*   Wihphi  = (f16*)(ws + SB + 3440640);     // 2048*1056 f16 = 1,081,344 fl (setup only)
    f16*   Wihplo  = (f16*)(ws + SB + 4521984);     // ends SB+5,603,328
    float* rawg    = ws + SB + 3440640;             // scan only: 4*512*2112 = 4,325,376 fl, ends SB+7,766,016
    float* gpart   = ws + SB + 5603328;             // setup partials (gx0: 2*512*2048, E: 4*48*2048), ends SB+7,700,480

    // ---- workspace-gated split-K config for x0 ----
    int ZX0, ksl_x0;
    if      (ws_size >= (size_t)52898048){ ZX0=8; ksl_x0=800;  }
    else if (ws_size >= (size_t)44476672){ ZX0=4; ksl_x0=1600; }
    else                                 { ZX0=2; ksl_x0=3168; }
    const int ZGX = 2, ksl_gx = 544;
    const int ZE  = 4, ksl_e  = 256;
    const int ZSC = 4, ksl_sc = 128;    // scan split-K: 4 K-slices of 128 -> 1056 blocks (4/CU)

    // ---- setup ----
    k_prep<<<8,256,0,stream>>>(bih,bhh,bp,Wih,bias2p,biascat,wl);
    k_cls<<<K*B,64,0,stream>>>(S,R,clsW,clsb,Y);
    k_curr_action<<<(B*C+255)/256,256,0,stream>>>(Y,outca);
    k_cvtY<<<(B*144+255)/256,256,0,stream>>>(Y,Yhi,Ylo);
    k_dur0<<<B,256,0,stream>>>(R,durW,durb,outpad);
    // linW -> transposed hi/lo [1088][6304]
    k_bt_build<<<dim3((FK+31)/32,(1088+31)/32),256,0,stream>>>(linW,lwthi,lwtlo,6288,1025,1025,1088,FK,1.f);
    // x0 = feat @ linW  (A gathered from Y/S/R, split-K ZX0, z-major XCD swizzle)
    k_mfma<1><<<8*17*ZX0,256,0,stream>>>(nullptr,nullptr,lwthi,lwtlo,x0part,nullptr,
                                         512,1028,FK,0,FK,1028,ksl_x0,(size_t)512*1028,8,ZX0,1,
                                         Yhi,Ylo,S,R);
    k_redcvt<<<(512*KP+255)/256,256,0,stream>>>(x0part,ZX0,(size_t)512*1028,linb,x0hi,x0lo);
    // Wih^T (gate-perm rows) hi/lo   [lwt region is dead from here]
    k_permrows<<<(G4H*KP+255)/256,256,0,stream>>>(Wih,Wihphi,Wihplo,DP1,KP,DP1);
    // gx0 = x0 @ WihT (split-K ZGX, partials in gpart)
    k_mfma<0><<<8*32*ZGX,256,0,stream>>>(x0hi,x0lo,Wihphi,Wihplo,gpart,nullptr,
                                         512,G4H,KP,KP,KP,G4H,ksl_gx,(size_t)512*G4H,8,ZGX,0,
                                         nullptr,nullptr,nullptr,nullptr);
    k_lstm0<<<(B*H+255)/256,256,0,stream>>>(gpart,ZGX,(size_t)512*G4H,bias2p,c,hAhi,hAlo);
    k_cvt<<<(48*KP+255)/256,256,0,stream>>>(embed,embhi,emblo,48,1024,1024,KP,1.f);
    // E = embed @ WihT + bias2p (partials reuse gpart after k_lstm0)
    k_mfma<0><<<1*32*ZE,256,0,stream>>>(embhi,emblo,Wihphi,Wihplo,gpart,nullptr,
                                        48,G4H,KP,KP,KP,G4H,ksl_e,(size_t)48*G4H,1,ZE,0,
                                        nullptr,nullptr,nullptr,nullptr);
    k_red<<<(48*G4H+255)/256,256,0,stream>>>(E,gpart,ZE,(size_t)48*G4H,48,G4H,G4H,bias2p);
    // V[k,b,:] = (S_k @ Wattn^T)/32  -- removes q (1024 cols) from the step GEMM
    k_cvt<<<(1536*1024+255)/256,256,0,stream>>>(S,Shi,Slo,1536,1024,1024,1024,1.f);
    k_cvt<<<(512*1024+255)/256,256,0,stream>>>(Wattn,watthi,wattlo,512,1024,1024,1024,0.03125f);
    k_mfma<0><<<24*8,256,0,stream>>>(Shi,Slo,watthi,wattlo,Vbuf,nullptr,
                                     1536,512,1024,1024,1024,512,1024,0,24,1,0,
                                     nullptr,nullptr,nullptr,nullptr);
    // Wct2 [2112][512]: rows 0..2047 Whh perm | 2048..2095 Wp^T | 2096..2111 pad 0
    k_permrows<<<(G4H*512+255)/256,256,0,stream>>>(Whh,Wcthi,Wctlo,H,H,H);
    k_bt_build<<<dim3(16,2),256,0,stream>>>(Wp,Wcthi+(size_t)2048*512,Wctlo+(size_t)2048*512,
                                            512,48,48,48,512,1.f);
    k_zeroh<<<32,256,0,stream>>>(Wcthi+(size_t)2096*512,Wctlo+(size_t)2096*512,16*512);

    // ---- scan ----
    size_t pstr = (size_t)512*NC;
    f16 *hCurHi=hAhi, *hCurLo=hAlo, *hPrvHi=hBhi, *hPrvLo=hBlo;
    for (int t=0;t<T;t++){
        k_mfma<0><<<8*33*ZSC,256,0,stream>>>(hCurHi,hCurLo,Wcthi,Wctlo,rawg,nullptr,
                                             512,NCV,H,H,H,NC,ksl_sc,pstr,8,ZSC,0,
                                             nullptr,nullptr,nullptr,nullptr);
        k_postapply<4><<<B,512,0,stream>>>(rawg,pstr,S,Vbuf,hCurHi,hCurLo,
                                        (t==0)?nullptr:hPrvHi,(t==0)?nullptr:hPrvLo,
                                        E,wl,biascat,Wdur,bdur,
                                        outlab,outprobs,outatt,outpad,
                                        c,hPrvHi,hPrvLo,t,(t<T-1)?1:0);
        f16* th=hPrvHi; hPrvHi=hCurHi; hCurHi=th;
        f16* tl=hPrvLo; hPrvLo=hCurLo; hCurLo=tl;
    }
}

// Round 6
// 877.716 us; speedup vs baseline: 1.1108x; 1.1108x over previous
//
#include <hip/hip_runtime.h>
#include <math.h>

#define B 512
#define D 1024
#define H 512
#define C 48
#define K 3
#define T 25
#define DP1 1025
#define G4H 2048
#define NC 2112         // step GEMM N (padded): 2048 gates | 48 logits | 16 pad
#define NCV 2096        // valid cols
#define KP 1056         // padded K for x0/embed rows (multiple of 32)
#define FK 6304         // padded feat-K (6288 -> 6304)

typedef _Float16 f16;
typedef _Float16 half8 __attribute__((ext_vector_type(8)));
typedef float floatx4 __attribute__((ext_vector_type(4)));

__device__ __forceinline__ float sigf(float x){ return 1.0f/(1.0f+__expf(-x)); }
// NaN-safe fast tanh: tanh(x) = sign(x)*(1-t)/(1+t), t=exp(-2|x|) in (0,1]
__device__ __forceinline__ float tanhf_fast(float x){
    float t = __expf(-2.0f*fabsf(x));
    float r = (1.0f-t)/(1.0f+t);
    return x<0.f ? -r : r;
}

// ================= split-f16 MFMA GEMM: 64x64 tile, BK=32, 4 waves =================
// Double-buffered LDS, XCD swizzle (n-chunked or z-major), split-K via Z.

template<int MODE>
__device__ __forceinline__ void mf_load(
    const f16* __restrict__ Ahi, const f16* __restrict__ Alo,
    const f16* __restrict__ Bhi, const f16* __restrict__ Blo,
    int M, int lda, int ldb, int m0, int n0, int kbase, int k0, int t,
    const f16* __restrict__ Yh, const f16* __restrict__ Yl,
    const float* __restrict__ Sf, const float* __restrict__ Rf,
    half8& rah, half8& ral, half8& rbh, half8& rbl)
{
    int r = t>>2, seg = t&3;
    int kk = k0 + seg*8;
    {
        size_t off = (size_t)(n0+r)*ldb + kbase + kk;
        rbh = *(const half8*)(Bhi + off);
        rbl = *(const half8*)(Blo + off);
    }
    int m = m0 + r;
    if (MODE==0){
        if (m < M){
            size_t off = (size_t)m*lda + kbase + kk;
            rah = *(const half8*)(Ahi + off);
            ral = *(const half8*)(Alo + off);
        } else {
            #pragma unroll
            for (int i=0;i<8;i++){ rah[i]=(f16)0; ral[i]=(f16)0; }
        }
    } else {
        int kabs = kbase + kk;   // 8-aligned; source runs never straddle boundaries
        if (kabs < 144){
            rah = *(const half8*)(Yh + (size_t)m*144 + kabs);
            ral = *(const half8*)(Yl + (size_t)m*144 + kabs);
        } else if (kabs < 6288){
            int kp = kabs - 144;
            const float* src = (kp < 3*D)
                ? (Sf + (size_t)(kp>>10)*(B*D) + (size_t)m*D + (kp&(D-1)))
                : (Rf + (size_t)((kp-3*D)>>10)*(B*D) + (size_t)m*D + ((kp-3*D)&(D-1)));
            float4 f0 = *(const float4*)src;
            float4 f1 = *(const float4*)(src+4);
            float fv[8]={f0.x,f0.y,f0.z,f0.w,f1.x,f1.y,f1.z,f1.w};
            #pragma unroll
            for (int i=0;i<8;i++){
                f16 h=(f16)fv[i];
                rah[i]=h; ral[i]=(f16)(fv[i]-(float)h);
            }
        } else {
            #pragma unroll
            for (int i=0;i<8;i++){ rah[i]=(f16)0; ral[i]=(f16)0; }
        }
    }
}

// MODE-1 (x0 gather) kernel: classic __syncthreads dbuf (conversion consumes loads eagerly).
template<int MODE>
__global__ __launch_bounds__(256)
void k_mfma(const f16* __restrict__ Ahi, const f16* __restrict__ Alo,
            const f16* __restrict__ Bhi, const f16* __restrict__ Blo,
            float* __restrict__ Cc, const float* __restrict__ bias,
            int M, int Nvalid, int Ktot, int lda, int ldb, int ldc,
            int ksl, size_t cstride, int MB, int Z, int zmaj,
            const f16* __restrict__ Yh, const f16* __restrict__ Yl,
            const float* __restrict__ Sf, const float* __restrict__ Rf)
{
    __shared__ __align__(16) f16 Ash[2][64][40];
    __shared__ __align__(16) f16 Asl[2][64][40];
    __shared__ __align__(16) f16 Bsh[2][64][40];
    __shared__ __align__(16) f16 Bsl[2][64][40];
    int t = threadIdx.x;
    int mblk, nblk, z;
    if (zmaj){
        z = blockIdx.x % Z;
        int rest = blockIdx.x / Z;
        mblk = rest % MB; nblk = rest / MB;
    } else {
        int chunk = gridDim.x >> 3;
        int g = (blockIdx.x & 7)*chunk + (blockIdx.x >> 3);
        int mz = g % (MB*Z);
        nblk = g / (MB*Z);
        mblk = mz / Z;
        z    = mz % Z;
    }
    int m0 = mblk*64, n0 = nblk*64;
    int kbase = z*ksl;
    int kcnt = (z==Z-1)? (Ktot-kbase) : ksl;
    int nIter = kcnt >> 5;
    int r = t>>2, seg = t&3;
    half8 rah, ral, rbh, rbl;
    mf_load<MODE>(Ahi,Alo,Bhi,Blo,M,lda,ldb,m0,n0,kbase,0,t,Yh,Yl,Sf,Rf,rah,ral,rbh,rbl);
    int lane = t&63, wv = t>>6;
    int lrow = lane&15, quad = lane>>4;
    floatx4 acc[4] = {};
    int cur = 0;
    for (int it=0; it<nIter; ++it){
        *(half8*)&Ash[cur][r][seg*8] = rah;
        *(half8*)&Asl[cur][r][seg*8] = ral;
        *(half8*)&Bsh[cur][r][seg*8] = rbh;
        *(half8*)&Bsl[cur][r][seg*8] = rbl;
        if (it+1 < nIter)
            mf_load<MODE>(Ahi,Alo,Bhi,Blo,M,lda,ldb,m0,n0,kbase,(it+1)<<5,t,Yh,Yl,Sf,Rf,rah,ral,rbh,rbl);
        __syncthreads();
        half8 ah = *(const half8*)&Ash[cur][wv*16+lrow][quad*8];
        half8 al = *(const half8*)&Asl[cur][wv*16+lrow][quad*8];
        #pragma unroll
        for (int j=0;j<4;j++){
            half8 bh = *(const half8*)&Bsh[cur][j*16+lrow][quad*8];
            half8 bl = *(const half8*)&Bsl[cur][j*16+lrow][quad*8];
            acc[j] = __builtin_amdgcn_mfma_f32_16x16x32_f16(ah, bh, acc[j], 0,0,0);
            acc[j] = __builtin_amdgcn_mfma_f32_16x16x32_f16(al, bh, acc[j], 0,0,0);
            acc[j] = __builtin_amdgcn_mfma_f32_16x16x32_f16(ah, bl, acc[j], 0,0,0);
        }
        cur ^= 1;
    }
    float* Cz = Cc + (size_t)z*cstride;
    #pragma unroll
    for (int j=0;j<4;j++){
        int col = n0 + j*16 + lrow;
        if (col >= Nvalid) continue;
        float bv = bias ? bias[col] : 0.f;
        #pragma unroll
        for (int i=0;i<4;i++){
            int row = m0 + wv*16 + quad*4 + i;
            if (row < M) Cz[(size_t)row*ldc + col] = acc[j][i] + bv;
        }
    }
}

// MODE-0 kernel with counted-vmcnt pipeline: raw s_barrier + lgkmcnt-only wait so the
// next-tile global prefetch stays in flight across the barrier (T3/T4 minimum form).
__global__ __launch_bounds__(256)
void k_mfma0(const f16* __restrict__ Ahi, const f16* __restrict__ Alo,
             const f16* __restrict__ Bhi, const f16* __restrict__ Blo,
             float* __restrict__ Cc, const float* __restrict__ bias,
             int M, int Nvalid, int Ktot, int lda, int ldb, int ldc,
             int ksl, size_t cstride, int MB, int Z)
{
    __shared__ __align__(16) f16 Ash[2][64][40];
    __shared__ __align__(16) f16 Asl[2][64][40];
    __shared__ __align__(16) f16 Bsh[2][64][40];
    __shared__ __align__(16) f16 Bsl[2][64][40];
    int t = threadIdx.x;
    int chunk = gridDim.x >> 3;
    int g = (blockIdx.x & 7)*chunk + (blockIdx.x >> 3);
    int mz = g % (MB*Z);
    int nblk = g / (MB*Z);
    int mblk = mz / Z;
    int z    = mz % Z;
    int m0 = mblk*64, n0 = nblk*64;
    int kbase = z*ksl;
    int kcnt = (z==Z-1)? (Ktot-kbase) : ksl;
    int nIter = kcnt >> 5;
    int r = t>>2, seg = t&3;
    half8 rah, ral, rbh, rbl;
    mf_load<0>(Ahi,Alo,Bhi,Blo,M,lda,ldb,m0,n0,kbase,0,t,
               nullptr,nullptr,nullptr,nullptr,rah,ral,rbh,rbl);
    int lane = t&63, wv = t>>6;
    int lrow = lane&15, quad = lane>>4;
    floatx4 acc[4] = {};
    int cur = 0;
    for (int it=0; it<nIter; ++it){
        // ds_writes read the regs at issue; safe to overwrite them with the prefetch below.
        *(half8*)&Ash[cur][r][seg*8] = rah;
        *(half8*)&Asl[cur][r][seg*8] = ral;
        *(half8*)&Bsh[cur][r][seg*8] = rbh;
        *(half8*)&Bsl[cur][r][seg*8] = rbl;
        if (it+1 < nIter)
            mf_load<0>(Ahi,Alo,Bhi,Blo,M,lda,ldb,m0,n0,kbase,(it+1)<<5,t,
                       nullptr,nullptr,nullptr,nullptr,rah,ral,rbh,rbl);
        // wait only LDS writes; raw barrier does NOT drain vmcnt -> prefetch stays in flight
        asm volatile("s_waitcnt lgkmcnt(0)" ::: "memory");
        __builtin_amdgcn_s_barrier();
        half8 ah = *(const half8*)&Ash[cur][wv*16+lrow][quad*8];
        half8 al = *(const half8*)&Asl[cur][wv*16+lrow][quad*8];
        #pragma unroll
        for (int j=0;j<4;j++){
            half8 bh = *(const half8*)&Bsh[cur][j*16+lrow][quad*8];
            half8 bl = *(const half8*)&Bsl[cur][j*16+lrow][quad*8];
            acc[j] = __builtin_amdgcn_mfma_f32_16x16x32_f16(ah, bh, acc[j], 0,0,0);
            acc[j] = __builtin_amdgcn_mfma_f32_16x16x32_f16(al, bh, acc[j], 0,0,0);
            acc[j] = __builtin_amdgcn_mfma_f32_16x16x32_f16(ah, bl, acc[j], 0,0,0);
        }
        cur ^= 1;
    }
    float* Cz = Cc + (size_t)z*cstride;
    #pragma unroll
    for (int j=0;j<4;j++){
        int col = n0 + j*16 + lrow;
        if (col >= Nvalid) continue;
        float bv = bias ? bias[col] : 0.f;
        #pragma unroll
        for (int i=0;i<4;i++){
            int row = m0 + wv*16 + quad*4 + i;
            if (row < M) Cz[(size_t)row*ldc + col] = acc[j][i] + bv;
        }
    }
}

// ================= setup kernels =================

__global__ void k_bt_build(const float* __restrict__ src, f16* __restrict__ hi, f16* __restrict__ lo,
                           int Ksrc, int Nsrc, int ld_src, int NB, int KB, float scale){
    __shared__ float tile[32][33];
    int k0 = blockIdx.x*32, n0 = blockIdx.y*32;
    int lx = threadIdx.x & 31, ly = threadIdx.x >> 5;
    for (int rr=0; rr<32; rr+=8){
        int k2 = k0+ly+rr, n = n0+lx;
        tile[ly+rr][lx] = (k2<Ksrc && n<Nsrc)? src[(size_t)k2*ld_src+n]*scale : 0.f;
    }
    __syncthreads();
    for (int rr=0; rr<32; rr+=8){
        int n = n0+ly+rr, k2 = k0+lx;
        if (n<NB && k2<KB){
            float v = tile[lx][ly+rr];
            f16 h=(f16)v;
            hi[(size_t)n*KB+k2]=h;
            lo[(size_t)n*KB+k2]=(f16)(v-(float)h);
        }
    }
}

__global__ void k_permrows(const float* __restrict__ src, f16* __restrict__ hi, f16* __restrict__ lo,
                           int src_ld, int dst_ld, int kvalid){
    int idx = blockIdx.x*256+threadIdx.x;
    if (idx >= G4H*dst_ld) return;
    int p = idx/dst_ld, k2 = idx%dst_ld;
    int j = p>>2, g = p&3, gi = (g<<9)|j;
    float v = (k2<kvalid)? src[(size_t)gi*src_ld + k2] : 0.f;
    f16 h=(f16)v;
    hi[idx]=h; lo[idx]=(f16)(v-(float)h);
}

__global__ void k_cvt(const float* __restrict__ src, f16* __restrict__ hi, f16* __restrict__ lo,
                      int M, int ld_src, int nvalid, int ld_dst, float scale){
    int idx = blockIdx.x*256+threadIdx.x;
    if (idx >= M*ld_dst) return;
    int m = idx/ld_dst, n = idx%ld_dst;
    float v = (n<nvalid)? src[(size_t)m*ld_src+n]*scale : 0.f;
    f16 h=(f16)v; hi[idx]=h; lo[idx]=(f16)(v-(float)h);
}

__global__ void k_cvtY(const float* __restrict__ Y, f16* __restrict__ hi, f16* __restrict__ lo){
    int idx = blockIdx.x*256+threadIdx.x;
    if (idx >= B*144) return;
    int b = idx/144, k2 = idx%144;
    float v = Y[((size_t)(k2/C)*B + b)*C + (k2%C)];
    f16 h=(f16)v; hi[idx]=h; lo[idx]=(f16)(v-(float)h);
}

__global__ void k_zeroh(f16* a, f16* b2, int n){
    int i = blockIdx.x*256+threadIdx.x; if (i<n){ a[i]=(f16)0; b2[i]=(f16)0; }
}

__global__ void k_prep(const float* __restrict__ bih, const float* __restrict__ bhh,
                       const float* __restrict__ bp, const float* __restrict__ Wih,
                       float* __restrict__ bias2p, float* __restrict__ biascat,
                       float* __restrict__ wl){
    int i = blockIdx.x*256 + threadIdx.x;
    if (i < G4H){
        int g=i&3, j=i>>2; int gi=(g<<9)|j;
        bias2p[i]=bih[gi]+bhh[gi];
        wl[i]=Wih[(size_t)gi*DP1 + 1024];
    }
    if (i < C) biascat[i]=bp[i];
}

__global__ void k_cls(const float* __restrict__ S, const float* __restrict__ R,
                      const float* __restrict__ clsW, const float* __restrict__ clsb,
                      float* __restrict__ Y){
    int kb = blockIdx.x; int k = kb / B; int b = kb % B;
    int t = threadIdx.x; // 64
    __shared__ float sr[64];
    __shared__ float lg[C];
    __shared__ float mred[2];
    float acc = (t<C) ? clsb[k*C+t] : 0.f;
    const float* W = clsW + (size_t)k*2*D*C;
    for (int i0=0; i0<2*D; i0+=64){
        int i = i0 + t;
        sr[t] = (i < D) ? S[((size_t)k*B+b)*D + i] : R[((size_t)k*B+b)*D + (i-D)];
        __syncthreads();
        if (t < C){ for (int ii=0; ii<64; ++ii) acc += sr[ii]*W[(size_t)(i0+ii)*C + t]; }
        __syncthreads();
    }
    if (t<C) lg[t]=acc;
    __syncthreads();
    if (t==0){
        float m=lg[0]; for(int c2=1;c2<C;c2++) m=fmaxf(m,lg[c2]);
        float s=0.f; for(int c2=0;c2<C;c2++) s+=expf(lg[c2]-m);
        mred[0]=m; mred[1]=s;
    }
    __syncthreads();
    if (t<C) Y[((size_t)k*B+b)*C + t] = expf(lg[t]-mred[0])/mred[1];
}

__global__ void k_curr_action(const float* __restrict__ Y, float* __restrict__ outca){
    int i = blockIdx.x*256+threadIdx.x; if (i>=B*C) return;
    int b=i/C, c2=i%C;
    outca[i] = Y[((size_t)0*B+b)*C+c2] + Y[((size_t)1*B+b)*C+c2] + Y[((size_t)2*B+b)*C+c2];
}

__global__ void k_dur0(const float* __restrict__ R, const float* __restrict__ durW,
                       const float* __restrict__ durb, float* __restrict__ outpad){
    int b = blockIdx.x; int t = threadIdx.x;
    __shared__ float red[256];
    float p=0.f;
    for (int i=t; i<K*D; i+=256){ int k=i>>10, d=i&1023; p += R[((size_t)k*B+b)*D+d]*durW[i]; }
    red[t]=p; __syncthreads();
    for (int s=128;s>0;s>>=1){ if(t<s) red[t]+=red[t+s]; __syncthreads(); }
    if (t==0) outpad[(size_t)b*(T+1)] = red[0] + durb[0];
}

__global__ void k_red(float* __restrict__ dst, const float* __restrict__ src, int parts, size_t pstride,
                      int M, int Nld, int Nvalid, const float* __restrict__ bias){
    int idx = blockIdx.x*256+threadIdx.x;
    if (idx >= M*Nld) return;
    int n = idx % Nld;
    float v = 0.f;
    if (n < Nvalid){
        for (int p=0;p<parts;p++) v += src[(size_t)p*pstride + idx];
        if (bias) v += bias[n];
    }
    dst[idx]=v;
}

__global__ void k_redcvt(const float* __restrict__ src, int parts, size_t pstride,
                         const float* __restrict__ bias, f16* __restrict__ hi, f16* __restrict__ lo){
    int idx = blockIdx.x*256+threadIdx.x;
    if (idx >= 512*KP) return;
    int m = idx/KP, n = idx%KP;
    float v = 0.f;
    if (n < DP1){
        for (int p=0;p<parts;p++) v += src[(size_t)p*pstride + (size_t)m*1028 + n];
        v += bias[n];
    }
    f16 h=(f16)v; hi[idx]=h; lo[idx]=(f16)(v-(float)h);
}

// ================= scan kernels =================

// fused split-K reduce + bias + LSTM step 0
__global__ void k_lstm0(const float* __restrict__ gxp, int parts, size_t pstride,
                        const float* __restrict__ bias2p,
                        float* __restrict__ c, f16* __restrict__ hhi, f16* __restrict__ hlo){
    int idx = blockIdx.x*256+threadIdx.x; if (idx>=B*H) return;
    int r=idx>>9, j=idx&511;
    float4 g = *(const float4*)&gxp[(size_t)r*G4H + (j<<2)];
    if (parts==2){
        float4 g2 = *(const float4*)&gxp[pstride + (size_t)r*G4H + (j<<2)];
        g.x+=g2.x; g.y+=g2.y; g.z+=g2.z; g.w+=g2.w;
    }
    float4 bb = *(const float4*)&bias2p[j<<2];
    g.x+=bb.x; g.y+=bb.y; g.z+=bb.z; g.w+=bb.w;
    float cn = sigf(g.x)*tanhf_fast(g.z);
    c[idx]=cn;
    float hv = sigf(g.w)*tanhf_fast(cn);
    f16 h=(f16)hv; hhi[idx]=h; hlo[idx]=(f16)(hv-(float)h);
}

// fused: softmax/argmax + probs + attention (via precomputed V) + dur head + LSTM cell.
// 512 threads; wave-shfl reductions; PARTS-way split-K partial sum inline.
template<int PARTS>
__global__ void k_postapply(const float* __restrict__ rawg, size_t pstride,
                       const float* __restrict__ S, const float* __restrict__ V,
                       const f16* __restrict__ hchi, const f16* __restrict__ hclo,
                       const f16* __restrict__ holdhi, const f16* __restrict__ holdlo,
                       const float* __restrict__ E, const float* __restrict__ wl,
                       const float* __restrict__ biascat,
                       const float* __restrict__ Wdur, const float* __restrict__ bdur,
                       float* __restrict__ outlab, float* __restrict__ outprobs,
                       float* __restrict__ outatt, float* __restrict__ outpad,
                       float* __restrict__ c, f16* __restrict__ hNhi, f16* __restrict__ hNlo,
                       int tstep, int doLstm)
{
    int b=blockIdx.x, t=threadIdx.x;
    int lane=t&63, wv=t>>6;
    __shared__ float aw[3];
    __shared__ float redw[4][8];
    __shared__ int sbest;
    __shared__ float sdv;
    const float* z0 = rawg + (size_t)b*NC;
    // logits softmax/argmax on wave 0
    if (t<64){
        float lgv = -3.0e38f;
        if (t<C){
            float v = 0.f;
            #pragma unroll
            for (int p=0;p<PARTS;p++) v += z0[(size_t)p*pstride + G4H + t];
            lgv = v + biascat[t];
        }
        float m = lgv; int bi = t;
        #pragma unroll
        for (int s2=32;s2>0;s2>>=1){
            float om=__shfl_xor(m,s2); int ob=__shfl_xor(bi,s2);
            if (om>m || (om==m && ob<bi)){ m=om; bi=ob; }
        }
        float e=(t<C)? __expf(lgv-m):0.f;
        float ss=e;
        #pragma unroll
        for (int s2=32;s2>0;s2>>=1) ss+=__shfl_xor(ss,s2);
        if (t<C) outprobs[(size_t)b*(T*C)+tstep*C+t]=e/ss;
        if (t==0){
            sbest=bi;
            outlab[(size_t)tstep*B+b]=(float)bi;
        }
    }
    // attention scores via precomputed V: p_k = h . V[k,b,:]
    float hv_t = (float)hchi[(size_t)b*H + t] + (float)hclo[(size_t)b*H + t];
    float p0 = hv_t * V[((size_t)(0*B+b))*H + t];
    float p1 = hv_t * V[((size_t)(1*B+b))*H + t];
    float p2 = hv_t * V[((size_t)(2*B+b))*H + t];
    #pragma unroll
    for (int s2=32;s2>0;s2>>=1){
        p0 += __shfl_xor(p0,s2); p1 += __shfl_xor(p1,s2); p2 += __shfl_xor(p2,s2);
    }
    if (lane==0){ redw[0][wv]=p0; redw[1][wv]=p1; redw[2][wv]=p2; }
    __syncthreads();
    if (t==0){
        float a0=0.f,a1=0.f,a2=0.f;
        #pragma unroll
        for (int w=0;w<8;w++){ a0+=redw[0][w]; a1+=redw[1][w]; a2+=redw[2][w]; }
        float m=fmaxf(a0,fmaxf(a1,a2));
        float e0=__expf(a0-m), e1=__expf(a1-m), e2=__expf(a2-m);
        float si=1.f/(e0+e1+e2);
        aw[0]=e0*si; aw[1]=e1*si; aw[2]=e2*si;
    }
    __syncthreads();
    float a0=aw[0],a1=aw[1],a2=aw[2];
    const float* S0  = S + (size_t)b*D;
    const float* S1  = S0 + (size_t)B*D;
    const float* S2p = S1 + (size_t)B*D;
    float dp = 0.f;
    float* attp = outatt + (size_t)tstep*B*D + (size_t)b*D;
    {
        int d = t<<1;   // single pass: 512 threads x float2 = 1024 floats = D
        float2 s0 = *(const float2*)(S0+d);
        float2 s1 = *(const float2*)(S1+d);
        float2 s2 = *(const float2*)(S2p+d);
        float2 w2 = *(const float2*)(Wdur+d);
        float2 av;
        av.x = a0*s0.x+a1*s1.x+a2*s2.x;
        av.y = a0*s0.y+a1*s1.y+a2*s2.y;
        *(float2*)(attp+d) = av;
        dp += av.x*w2.x+av.y*w2.y;
    }
    if (holdhi){
        float hvo = (float)holdhi[(size_t)b*H+t] + (float)holdlo[(size_t)b*H+t];
        dp += hvo * Wdur[D+t];
    }
    #pragma unroll
    for (int s2=32;s2>0;s2>>=1) dp += __shfl_xor(dp,s2);
    if (lane==0) redw[3][wv]=dp;
    __syncthreads();
    if (t==0){
        float dv=0.f;
        #pragma unroll
        for (int w=0;w<8;w++) dv+=redw[3][w];
        dv += bdur[0];
        outpad[(size_t)b*(T+1)+tstep+1]=dv; sdv=dv;
    }
    __syncthreads();
    if (doLstm){
        int lb=sbest; float dv=sdv;
        int j=t;   // 512 threads == H
        float4 g4 = *(const float4*)&z0[4*j];
        #pragma unroll
        for (int p=1;p<PARTS;p++){
            float4 h4 = *(const float4*)&z0[(size_t)p*pstride + 4*j];
            g4.x+=h4.x; g4.y+=h4.y; g4.z+=h4.z; g4.w+=h4.w;
        }
        float4 e4 = *(const float4*)&E[(size_t)lb*G4H+4*j];
        float4 w4 = *(const float4*)&wl[4*j];
        float gi = g4.x+e4.x+dv*w4.x;
        float gf = g4.y+e4.y+dv*w4.y;
        float gg = g4.z+e4.z+dv*w4.z;
        float go = g4.w+e4.w+dv*w4.w;
        size_t ci=(size_t)b*H+j;
        float cn = sigf(gf)*c[ci] + sigf(gi)*tanhf_fast(gg);
        c[ci]=cn;
        float hv = sigf(go)*tanhf_fast(cn);
        f16 hh=(f16)hv;
        hNhi[ci]=hh; hNlo[ci]=(f16)(hv-(float)hh);
    }
}

// ================= host =================

extern "C" void kernel_launch(void* const* d_in, const int* in_sizes, int n_in,
                              void* d_out, int out_size, void* d_ws, size_t ws_size,
                              hipStream_t stream) {
    const float* S    = (const float*)d_in[0];
    const float* R    = (const float*)d_in[1];
    const float* clsW = (const float*)d_in[2];
    const float* clsb = (const float*)d_in[3];
    const float* durW = (const float*)d_in[4];
    const float* durb = (const float*)d_in[5];
    const float* linW = (const float*)d_in[6];
    const float* linb = (const float*)d_in[7];
    const float* Wih  = (const float*)d_in[8];
    const float* Whh  = (const float*)d_in[9];
    const float* bih  = (const float*)d_in[10];
    const float* bhh  = (const float*)d_in[11];
    const float* Wp   = (const float*)d_in[12];
    const float* bp   = (const float*)d_in[13];
    const float* Wdur = (const float*)d_in[14];
    const float* bdur = (const float*)d_in[15];
    const float* embed= (const float*)d_in[16];
    const float* Wattn= (const float*)d_in[17];

    float* out = (float*)d_out;
    float* outlab   = out;                 // [T,B]
    float* outprobs = out + 12800;         // [B,T,C]
    float* outca    = out + 627200;        // [B,C]
    float* outpad   = out + 651776;        // [B,T+1]
    float* outatt   = out + 665088;        // [T,B,D]

    float* ws = (float*)d_ws;
    // persistent block
    float* E       = ws + 0;               // 98,304
    float* wl      = ws + 98304;           // 2,048
    float* bias2p  = ws + 100352;          // 2,048
    float* biascat = ws + 102400;          // 64
    float* c       = ws + 102464;          // 262,144
    f16*   hAhi    = (f16*)(ws + 364608);  // 262,144 f16
    f16*   hAlo    = (f16*)(ws + 495680);
    f16*   hBhi    = (f16*)(ws + 626752);
    f16*   hBlo    = (f16*)(ws + 757824);
    f16*   Yhi     = (f16*)(ws + 889920);  // 512*144 f16
    f16*   Ylo     = (f16*)(ws + 926784);
    float* Y       = ws + 963648;          // 73,728 -> ends 1,037,376
    f16*   watthi  = (f16*)(ws + 1037376); // 512*1024 f16 = 262,144 fl
    f16*   wattlo  = (f16*)(ws + 1299520); // ends 1,561,664 < 1,563,712
    f16*   x0hi    = (f16*)(ws + 1563712); // 512*1056 f16
    f16*   x0lo    = (f16*)(ws + 1834048);
    f16*   embhi   = (f16*)(ws + 2104384); // 48*1056 f16
    f16*   emblo   = (f16*)(ws + 2129728);
    // big scratch region, time-multiplexed (within the 40.26 MB floor):
    //  stage1 (x0): linWt hi/lo [SB .. SB+6,858,752) + x0part [SB+6,858,752 ..)
    //  stage2: Wct2 | S hi/lo | V | Wihp (setup) / rawg 2-parts (scan, overlays dead Wihp)
    //          gpart (gx0/E partials) after Wihp.
    const size_t SB = 2155072;
    f16*   lwthi   = (f16*)(ws + SB);               // 1088*6304 f16
    f16*   lwtlo   = (f16*)(ws + SB + 3429376);
    float* x0part  = ws + SB + 6858752;             // ZX0*512*1028 (ws-gated)
    f16*   Wcthi   = (f16*)(ws + SB);               // 2112*512 f16 = 540,672 fl
    f16*   Wctlo   = (f16*)(ws + SB + 540672);      // ends SB+1,081,344
    f16*   Shi     = (f16*)(ws + SB + 1081344);     // 1536*1024 f16 = 786,432 fl
    f16*   Slo     = (f16*)(ws + SB + 1867776);     // ends SB+2,654,208
    float* Vbuf    = ws + SB + 2654208;             // 786,432 fl, ends SB+3,440,640
    f16*   Wihphi  = (f16*)(ws + SB + 3440640);     // 2048*1056 f16 = 1,081,344 fl (setup only)
    f16*   Wihplo  = (f16*)(ws + SB + 4521984);     // ends SB+5,603,328
    float* rawg    = ws + SB + 3440640;             // scan only: 2*512*2112 = 2,162,688 fl (overlays dead Wihp)
    float* gpart   = ws + SB + 5603328;             // setup partials (gx0: 2*512*2048, E: 4*48*2048)

    // ---- workspace-gated split-K config for x0 ----
    int ZX0, ksl_x0;
    if      (ws_size >= (size_t)52898048){ ZX0=8; ksl_x0=800;  }
    else if (ws_size >= (size_t)44476672){ ZX0=4; ksl_x0=1600; }
    else                                 { ZX0=2; ksl_x0=3168; }
    const int ZGX = 2, ksl_gx = 544;
    const int ZE  = 4, ksl_e  = 256;
    const int ZSC = 2, ksl_sc = 256;    // scan split-K: 2 (measured best; 4 regressed r5)

    // ---- setup ----
    k_prep<<<8,256,0,stream>>>(bih,bhh,bp,Wih,bias2p,biascat,wl);
    k_cls<<<K*B,64,0,stream>>>(S,R,clsW,clsb,Y);
    k_curr_action<<<(B*C+255)/256,256,0,stream>>>(Y,outca);
    k_cvtY<<<(B*144+255)/256,256,0,stream>>>(Y,Yhi,Ylo);
    k_dur0<<<B,256,0,stream>>>(R,durW,durb,outpad);
    // linW -> transposed hi/lo [1088][6304]
    k_bt_build<<<dim3((FK+31)/32,(1088+31)/32),256,0,stream>>>(linW,lwthi,lwtlo,6288,1025,1025,1088,FK,1.f);
    // x0 = feat @ linW  (A gathered from Y/S/R, split-K ZX0, z-major XCD swizzle)
    k_mfma<1><<<8*17*ZX0,256,0,stream>>>(nullptr,nullptr,lwthi,lwtlo,x0part,nullptr,
                                         512,1028,FK,0,FK,1028,ksl_x0,(size_t)512*1028,8,ZX0,1,
                                         Yhi,Ylo,S,R);
    k_redcvt<<<(512*KP+255)/256,256,0,stream>>>(x0part,ZX0,(size_t)512*1028,linb,x0hi,x0lo);
    // Wih^T (gate-perm rows) hi/lo   [lwt region is dead from here]
    k_permrows<<<(G4H*KP+255)/256,256,0,stream>>>(Wih,Wihphi,Wihplo,DP1,KP,DP1);
    // gx0 = x0 @ WihT (split-K ZGX, partials in gpart; counted-vmcnt kernel)
    k_mfma0<<<8*32*ZGX,256,0,stream>>>(x0hi,x0lo,Wihphi,Wihplo,gpart,nullptr,
                                       512,G4H,KP,KP,KP,G4H,ksl_gx,(size_t)512*G4H,8,ZGX);
    k_lstm0<<<(B*H+255)/256,256,0,stream>>>(gpart,ZGX,(size_t)512*G4H,bias2p,c,hAhi,hAlo);
    k_cvt<<<(48*KP+255)/256,256,0,stream>>>(embed,embhi,emblo,48,1024,1024,KP,1.f);
    // E = embed @ WihT + bias2p (partials reuse gpart after k_lstm0)
    k_mfma0<<<1*32*ZE,256,0,stream>>>(embhi,emblo,Wihphi,Wihplo,gpart,nullptr,
                                      48,G4H,KP,KP,KP,G4H,ksl_e,(size_t)48*G4H,1,ZE);
    k_red<<<(48*G4H+255)/256,256,0,stream>>>(E,gpart,ZE,(size_t)48*G4H,48,G4H,G4H,bias2p);
    // V[k,b,:] = (S_k @ Wattn^T)/32  -- removes q (1024 cols) from the step GEMM
    k_cvt<<<(1536*1024+255)/256,256,0,stream>>>(S,Shi,Slo,1536,1024,1024,1024,1.f);
    k_cvt<<<(512*1024+255)/256,256,0,stream>>>(Wattn,watthi,wattlo,512,1024,1024,1024,0.03125f);
    k_mfma0<<<24*8,256,0,stream>>>(Shi,Slo,watthi,wattlo,Vbuf,nullptr,
                                   1536,512,1024,1024,1024,512,1024,0,24,1);
    // Wct2 [2112][512]: rows 0..2047 Whh perm | 2048..2095 Wp^T | 2096..2111 pad 0
    k_permrows<<<(G4H*512+255)/256,256,0,stream>>>(Whh,Wcthi,Wctlo,H,H,H);
    k_bt_build<<<dim3(16,2),256,0,stream>>>(Wp,Wcthi+(size_t)2048*512,Wctlo+(size_t)2048*512,
                                            512,48,48,48,512,1.f);
    k_zeroh<<<32,256,0,stream>>>(Wcthi+(size_t)2096*512,Wctlo+(size_t)2096*512,16*512);

    // ---- scan ----
    size_t pstr = (size_t)512*NC;
    f16 *hCurHi=hAhi, *hCurLo=hAlo, *hPrvHi=hBhi, *hPrvLo=hBlo;
    for (int t=0;t<T;t++){
        k_mfma0<<<8*33*ZSC,256,0,stream>>>(hCurHi,hCurLo,Wcthi,Wctlo,rawg,nullptr,
                                           512,NCV,H,H,H,NC,ksl_sc,pstr,8,ZSC);
        k_postapply<2><<<B,512,0,stream>>>(rawg,pstr,S,Vbuf,hCurHi,hCurLo,
                                        (t==0)?nullptr:hPrvHi,(t==0)?nullptr:hPrvLo,
                                        E,wl,biascat,Wdur,bdur,
                                        outlab,outprobs,outatt,outpad,
                                        c,hPrvHi,hPrvLo,t,(t<T-1)?1:0);
        f16* th=hPrvHi; hPrvHi=hCurHi; hCurHi=th;
        f16* tl=hPrvLo; hPrvLo=hCurLo; hCurLo=tl;
    }
}

// Round 7
// 854.101 us; speedup vs baseline: 1.1415x; 1.0276x over previous
//
#include <hip/hip_runtime.h>
#include <math.h>

#define B 512
#define D 1024
#define H 512
#define C 48
#define K 3
#define T 25
#define DP1 1025
#define G4H 2048
#define NC 2112         // step GEMM N (padded): 2048 gates | 48 logits | 16 pad
#define NCV 2096        // valid cols
#define KP 1056         // padded K for x0/embed rows (multiple of 32)
#define FK 6304         // padded feat-K (6288 -> 6304)

typedef _Float16 f16;
typedef _Float16 half8 __attribute__((ext_vector_type(8)));
typedef float floatx4 __attribute__((ext_vector_type(4)));

__device__ __forceinline__ float sigf(float x){ return 1.0f/(1.0f+__expf(-x)); }
// NaN-safe fast tanh: tanh(x) = sign(x)*(1-t)/(1+t), t=exp(-2|x|) in (0,1]
__device__ __forceinline__ float tanhf_fast(float x){
    float t = __expf(-2.0f*fabsf(x));
    float r = (1.0f-t)/(1.0f+t);
    return x<0.f ? -r : r;
}

// ================= split-f16 MFMA GEMM kernels =================

template<int MODE>
__device__ __forceinline__ void mf_load(
    const f16* __restrict__ Ahi, const f16* __restrict__ Alo,
    const f16* __restrict__ Bhi, const f16* __restrict__ Blo,
    int M, int lda, int ldb, int m0, int n0, int kbase, int k0, int t,
    const f16* __restrict__ Yh, const f16* __restrict__ Yl,
    const float* __restrict__ Sf, const float* __restrict__ Rf,
    half8& rah, half8& ral, half8& rbh, half8& rbl)
{
    int r = t>>2, seg = t&3;
    int kk = k0 + seg*8;
    {
        size_t off = (size_t)(n0+r)*ldb + kbase + kk;
        rbh = *(const half8*)(Bhi + off);
        rbl = *(const half8*)(Blo + off);
    }
    int m = m0 + r;
    if (MODE==0){
        if (m < M){
            size_t off = (size_t)m*lda + kbase + kk;
            rah = *(const half8*)(Ahi + off);
            ral = *(const half8*)(Alo + off);
        } else {
            #pragma unroll
            for (int i=0;i<8;i++){ rah[i]=(f16)0; ral[i]=(f16)0; }
        }
    } else {
        int kabs = kbase + kk;   // 8-aligned; source runs never straddle boundaries
        if (kabs < 144){
            rah = *(const half8*)(Yh + (size_t)m*144 + kabs);
            ral = *(const half8*)(Yl + (size_t)m*144 + kabs);
        } else if (kabs < 6288){
            int kp = kabs - 144;
            const float* src = (kp < 3*D)
                ? (Sf + (size_t)(kp>>10)*(B*D) + (size_t)m*D + (kp&(D-1)))
                : (Rf + (size_t)((kp-3*D)>>10)*(B*D) + (size_t)m*D + ((kp-3*D)&(D-1)));
            float4 f0 = *(const float4*)src;
            float4 f1 = *(const float4*)(src+4);
            float fv[8]={f0.x,f0.y,f0.z,f0.w,f1.x,f1.y,f1.z,f1.w};
            #pragma unroll
            for (int i=0;i<8;i++){
                f16 h=(f16)fv[i];
                rah[i]=h; ral[i]=(f16)(fv[i]-(float)h);
            }
        } else {
            #pragma unroll
            for (int i=0;i<8;i++){ rah[i]=(f16)0; ral[i]=(f16)0; }
        }
    }
}

// MODE-1 (x0 gather) kernel: classic __syncthreads dbuf (conversion consumes loads eagerly).
template<int MODE>
__global__ __launch_bounds__(256)
void k_mfma(const f16* __restrict__ Ahi, const f16* __restrict__ Alo,
            const f16* __restrict__ Bhi, const f16* __restrict__ Blo,
            float* __restrict__ Cc, const float* __restrict__ bias,
            int M, int Nvalid, int Ktot, int lda, int ldb, int ldc,
            int ksl, size_t cstride, int MB, int Z, int zmaj,
            const f16* __restrict__ Yh, const f16* __restrict__ Yl,
            const float* __restrict__ Sf, const float* __restrict__ Rf)
{
    __shared__ __align__(16) f16 Ash[2][64][40];
    __shared__ __align__(16) f16 Asl[2][64][40];
    __shared__ __align__(16) f16 Bsh[2][64][40];
    __shared__ __align__(16) f16 Bsl[2][64][40];
    int t = threadIdx.x;
    int mblk, nblk, z;
    if (zmaj){
        z = blockIdx.x % Z;
        int rest = blockIdx.x / Z;
        mblk = rest % MB; nblk = rest / MB;
    } else {
        int chunk = gridDim.x >> 3;
        int g = (blockIdx.x & 7)*chunk + (blockIdx.x >> 3);
        int mz = g % (MB*Z);
        nblk = g / (MB*Z);
        mblk = mz / Z;
        z    = mz % Z;
    }
    int m0 = mblk*64, n0 = nblk*64;
    int kbase = z*ksl;
    int kcnt = (z==Z-1)? (Ktot-kbase) : ksl;
    int nIter = kcnt >> 5;
    int r = t>>2, seg = t&3;
    half8 rah, ral, rbh, rbl;
    mf_load<MODE>(Ahi,Alo,Bhi,Blo,M,lda,ldb,m0,n0,kbase,0,t,Yh,Yl,Sf,Rf,rah,ral,rbh,rbl);
    int lane = t&63, wv = t>>6;
    int lrow = lane&15, quad = lane>>4;
    floatx4 acc[4] = {};
    int cur = 0;
    for (int it=0; it<nIter; ++it){
        *(half8*)&Ash[cur][r][seg*8] = rah;
        *(half8*)&Asl[cur][r][seg*8] = ral;
        *(half8*)&Bsh[cur][r][seg*8] = rbh;
        *(half8*)&Bsl[cur][r][seg*8] = rbl;
        if (it+1 < nIter)
            mf_load<MODE>(Ahi,Alo,Bhi,Blo,M,lda,ldb,m0,n0,kbase,(it+1)<<5,t,Yh,Yl,Sf,Rf,rah,ral,rbh,rbl);
        __syncthreads();
        half8 ah = *(const half8*)&Ash[cur][wv*16+lrow][quad*8];
        half8 al = *(const half8*)&Asl[cur][wv*16+lrow][quad*8];
        #pragma unroll
        for (int j=0;j<4;j++){
            half8 bh = *(const half8*)&Bsh[cur][j*16+lrow][quad*8];
            half8 bl = *(const half8*)&Bsl[cur][j*16+lrow][quad*8];
            acc[j] = __builtin_amdgcn_mfma_f32_16x16x32_f16(ah, bh, acc[j], 0,0,0);
            acc[j] = __builtin_amdgcn_mfma_f32_16x16x32_f16(al, bh, acc[j], 0,0,0);
            acc[j] = __builtin_amdgcn_mfma_f32_16x16x32_f16(ah, bl, acc[j], 0,0,0);
        }
        cur ^= 1;
    }
    float* Cz = Cc + (size_t)z*cstride;
    #pragma unroll
    for (int j=0;j<4;j++){
        int col = n0 + j*16 + lrow;
        if (col >= Nvalid) continue;
        float bv = bias ? bias[col] : 0.f;
        #pragma unroll
        for (int i=0;i<4;i++){
            int row = m0 + wv*16 + quad*4 + i;
            if (row < M) Cz[(size_t)row*ldc + col] = acc[j][i] + bv;
        }
    }
}

// MODE-0 kernel, templated N-tile (64 setup / 32 scan), counted-vmcnt pipeline:
// raw s_barrier + lgkmcnt-only wait so next-tile global prefetch stays in flight (T3/T4).
// NT=32 halves per-block work -> 2x blocks -> 4 blocks/CU for the scan GEMM (TLP).
template<int NT>
__global__ __launch_bounds__(256)
void k_mfma0(const f16* __restrict__ Ahi, const f16* __restrict__ Alo,
             const f16* __restrict__ Bhi, const f16* __restrict__ Blo,
             float* __restrict__ Cc, const float* __restrict__ bias,
             int M, int Nvalid, int Ktot, int lda, int ldb, int ldc,
             int ksl, size_t cstride, int MB, int Z)
{
    __shared__ __align__(16) f16 Ash[2][64][40];
    __shared__ __align__(16) f16 Asl[2][64][40];
    __shared__ __align__(16) f16 Bsh[2][NT][40];
    __shared__ __align__(16) f16 Bsl[2][NT][40];
    int t = threadIdx.x;
    int chunk = gridDim.x >> 3;
    int g = (blockIdx.x & 7)*chunk + (blockIdx.x >> 3);
    int mz = g % (MB*Z);
    int nblk = g / (MB*Z);
    int mblk = mz / Z;
    int z    = mz % Z;
    int m0 = mblk*64, n0 = nblk*NT;
    int kbase = z*ksl;
    int kcnt = (z==Z-1)? (Ktot-kbase) : ksl;
    int nIter = kcnt >> 5;
    int r = t>>2, seg = t&3;
    const bool ldB = (r < NT);
    half8 rah, ral, rbh, rbl;
    {
        int kk = seg*8;
        if (ldB){
            size_t off = (size_t)(n0+r)*ldb + kbase + kk;
            rbh = *(const half8*)(Bhi + off);
            rbl = *(const half8*)(Blo + off);
        }
        int m = m0 + r;
        if (m < M){
            size_t off = (size_t)m*lda + kbase + kk;
            rah = *(const half8*)(Ahi + off);
            ral = *(const half8*)(Alo + off);
        } else {
            #pragma unroll
            for (int i=0;i<8;i++){ rah[i]=(f16)0; ral[i]=(f16)0; }
        }
    }
    int lane = t&63, wv = t>>6;
    int lrow = lane&15, quad = lane>>4;
    floatx4 acc[NT/16] = {};
    int cur = 0;
    for (int it=0; it<nIter; ++it){
        *(half8*)&Ash[cur][r][seg*8] = rah;
        *(half8*)&Asl[cur][r][seg*8] = ral;
        if (ldB){
            *(half8*)&Bsh[cur][r][seg*8] = rbh;
            *(half8*)&Bsl[cur][r][seg*8] = rbl;
        }
        if (it+1 < nIter){
            int kk = ((it+1)<<5) + seg*8;
            if (ldB){
                size_t off = (size_t)(n0+r)*ldb + kbase + kk;
                rbh = *(const half8*)(Bhi + off);
                rbl = *(const half8*)(Blo + off);
            }
            int m = m0 + r;
            if (m < M){
                size_t off = (size_t)m*lda + kbase + kk;
                rah = *(const half8*)(Ahi + off);
                ral = *(const half8*)(Alo + off);
            }
        }
        // wait only LDS writes; raw barrier does NOT drain vmcnt -> prefetch stays in flight
        asm volatile("s_waitcnt lgkmcnt(0)" ::: "memory");
        __builtin_amdgcn_s_barrier();
        half8 ah = *(const half8*)&Ash[cur][wv*16+lrow][quad*8];
        half8 al = *(const half8*)&Asl[cur][wv*16+lrow][quad*8];
        #pragma unroll
        for (int j=0;j<NT/16;j++){
            half8 bh = *(const half8*)&Bsh[cur][j*16+lrow][quad*8];
            half8 bl = *(const half8*)&Bsl[cur][j*16+lrow][quad*8];
            acc[j] = __builtin_amdgcn_mfma_f32_16x16x32_f16(ah, bh, acc[j], 0,0,0);
            acc[j] = __builtin_amdgcn_mfma_f32_16x16x32_f16(al, bh, acc[j], 0,0,0);
            acc[j] = __builtin_amdgcn_mfma_f32_16x16x32_f16(ah, bl, acc[j], 0,0,0);
        }
        cur ^= 1;
    }
    float* Cz = Cc + (size_t)z*cstride;
    #pragma unroll
    for (int j=0;j<NT/16;j++){
        int col = n0 + j*16 + lrow;
        if (col >= Nvalid) continue;
        float bv = bias ? bias[col] : 0.f;
        #pragma unroll
        for (int i=0;i<4;i++){
            int row = m0 + wv*16 + quad*4 + i;
            if (row < M) Cz[(size_t)row*ldc + col] = acc[j][i] + bv;
        }
    }
}

// ================= setup kernels =================

__global__ void k_bt_build(const float* __restrict__ src, f16* __restrict__ hi, f16* __restrict__ lo,
                           int Ksrc, int Nsrc, int ld_src, int NB, int KB, float scale){
    __shared__ float tile[32][33];
    int k0 = blockIdx.x*32, n0 = blockIdx.y*32;
    int lx = threadIdx.x & 31, ly = threadIdx.x >> 5;
    for (int rr=0; rr<32; rr+=8){
        int k2 = k0+ly+rr, n = n0+lx;
        tile[ly+rr][lx] = (k2<Ksrc && n<Nsrc)? src[(size_t)k2*ld_src+n]*scale : 0.f;
    }
    __syncthreads();
    for (int rr=0; rr<32; rr+=8){
        int n = n0+ly+rr, k2 = k0+lx;
        if (n<NB && k2<KB){
            float v = tile[lx][ly+rr];
            f16 h=(f16)v;
            hi[(size_t)n*KB+k2]=h;
            lo[(size_t)n*KB+k2]=(f16)(v-(float)h);
        }
    }
}

__global__ void k_permrows(const float* __restrict__ src, f16* __restrict__ hi, f16* __restrict__ lo,
                           int src_ld, int dst_ld, int kvalid){
    int idx = blockIdx.x*256+threadIdx.x;
    if (idx >= G4H*dst_ld) return;
    int p = idx/dst_ld, k2 = idx%dst_ld;
    int j = p>>2, g = p&3, gi = (g<<9)|j;
    float v = (k2<kvalid)? src[(size_t)gi*src_ld + k2] : 0.f;
    f16 h=(f16)v;
    hi[idx]=h; lo[idx]=(f16)(v-(float)h);
}

__global__ void k_cvt(const float* __restrict__ src, f16* __restrict__ hi, f16* __restrict__ lo,
                      int M, int ld_src, int nvalid, int ld_dst, float scale){
    int idx = blockIdx.x*256+threadIdx.x;
    if (idx >= M*ld_dst) return;
    int m = idx/ld_dst, n = idx%ld_dst;
    float v = (n<nvalid)? src[(size_t)m*ld_src+n]*scale : 0.f;
    f16 h=(f16)v; hi[idx]=h; lo[idx]=(f16)(v-(float)h);
}

__global__ void k_cvtY(const float* __restrict__ Y, f16* __restrict__ hi, f16* __restrict__ lo){
    int idx = blockIdx.x*256+threadIdx.x;
    if (idx >= B*144) return;
    int b = idx/144, k2 = idx%144;
    float v = Y[((size_t)(k2/C)*B + b)*C + (k2%C)];
    f16 h=(f16)v; hi[idx]=h; lo[idx]=(f16)(v-(float)h);
}

__global__ void k_zeroh(f16* a, f16* b2, int n){
    int i = blockIdx.x*256+threadIdx.x; if (i<n){ a[i]=(f16)0; b2[i]=(f16)0; }
}

__global__ void k_prep(const float* __restrict__ bih, const float* __restrict__ bhh,
                       const float* __restrict__ bp, const float* __restrict__ Wih,
                       float* __restrict__ bias2p, float* __restrict__ biascat,
                       float* __restrict__ wl){
    int i = blockIdx.x*256 + threadIdx.x;
    if (i < G4H){
        int g=i&3, j=i>>2; int gi=(g<<9)|j;
        bias2p[i]=bih[gi]+bhh[gi];
        wl[i]=Wih[(size_t)gi*DP1 + 1024];
    }
    if (i < C) biascat[i]=bp[i];
}

__global__ void k_cls(const float* __restrict__ S, const float* __restrict__ R,
                      const float* __restrict__ clsW, const float* __restrict__ clsb,
                      float* __restrict__ Y){
    int kb = blockIdx.x; int k = kb / B; int b = kb % B;
    int t = threadIdx.x; // 64
    __shared__ float sr[64];
    __shared__ float lg[C];
    __shared__ float mred[2];
    float acc = (t<C) ? clsb[k*C+t] : 0.f;
    const float* W = clsW + (size_t)k*2*D*C;
    for (int i0=0; i0<2*D; i0+=64){
        int i = i0 + t;
        sr[t] = (i < D) ? S[((size_t)k*B+b)*D + i] : R[((size_t)k*B+b)*D + (i-D)];
        __syncthreads();
        if (t < C){ for (int ii=0; ii<64; ++ii) acc += sr[ii]*W[(size_t)(i0+ii)*C + t]; }
        __syncthreads();
    }
    if (t<C) lg[t]=acc;
    __syncthreads();
    if (t==0){
        float m=lg[0]; for(int c2=1;c2<C;c2++) m=fmaxf(m,lg[c2]);
        float s=0.f; for(int c2=0;c2<C;c2++) s+=expf(lg[c2]-m);
        mred[0]=m; mred[1]=s;
    }
    __syncthreads();
    if (t<C) Y[((size_t)k*B+b)*C + t] = expf(lg[t]-mred[0])/mred[1];
}

__global__ void k_curr_action(const float* __restrict__ Y, float* __restrict__ outca){
    int i = blockIdx.x*256+threadIdx.x; if (i>=B*C) return;
    int b=i/C, c2=i%C;
    outca[i] = Y[((size_t)0*B+b)*C+c2] + Y[((size_t)1*B+b)*C+c2] + Y[((size_t)2*B+b)*C+c2];
}

__global__ void k_dur0(const float* __restrict__ R, const float* __restrict__ durW,
                       const float* __restrict__ durb, float* __restrict__ outpad){
    int b = blockIdx.x; int t = threadIdx.x;
    __shared__ float red[256];
    float p=0.f;
    for (int i=t; i<K*D; i+=256){ int k=i>>10, d=i&1023; p += R[((size_t)k*B+b)*D+d]*durW[i]; }
    red[t]=p; __syncthreads();
    for (int s=128;s>0;s>>=1){ if(t<s) red[t]+=red[t+s]; __syncthreads(); }
    if (t==0) outpad[(size_t)b*(T+1)] = red[0] + durb[0];
}

__global__ void k_red(float* __restrict__ dst, const float* __restrict__ src, int parts, size_t pstride,
                      int M, int Nld, int Nvalid, const float* __restrict__ bias){
    int idx = blockIdx.x*256+threadIdx.x;
    if (idx >= M*Nld) return;
    int n = idx % Nld;
    float v = 0.f;
    if (n < Nvalid){
        for (int p=0;p<parts;p++) v += src[(size_t)p*pstride + idx];
        if (bias) v += bias[n];
    }
    dst[idx]=v;
}

__global__ void k_redcvt(const float* __restrict__ src, int parts, size_t pstride,
                         const float* __restrict__ bias, f16* __restrict__ hi, f16* __restrict__ lo){
    int idx = blockIdx.x*256+threadIdx.x;
    if (idx >= 512*KP) return;
    int m = idx/KP, n = idx%KP;
    float v = 0.f;
    if (n < DP1){
        for (int p=0;p<parts;p++) v += src[(size_t)p*pstride + (size_t)m*1028 + n];
        v += bias[n];
    }
    f16 h=(f16)v; hi[idx]=h; lo[idx]=(f16)(v-(float)h);
}

// ================= scan kernels =================

// fused split-K reduce + bias + LSTM step 0
__global__ void k_lstm0(const float* __restrict__ gxp, int parts, size_t pstride,
                        const float* __restrict__ bias2p,
                        float* __restrict__ c, f16* __restrict__ hhi, f16* __restrict__ hlo){
    int idx = blockIdx.x*256+threadIdx.x; if (idx>=B*H) return;
    int r=idx>>9, j=idx&511;
    float4 g = *(const float4*)&gxp[(size_t)r*G4H + (j<<2)];
    if (parts==2){
        float4 g2 = *(const float4*)&gxp[pstride + (size_t)r*G4H + (j<<2)];
        g.x+=g2.x; g.y+=g2.y; g.z+=g2.z; g.w+=g2.w;
    }
    float4 bb = *(const float4*)&bias2p[j<<2];
    g.x+=bb.x; g.y+=bb.y; g.z+=bb.z; g.w+=bb.w;
    float cn = sigf(g.x)*tanhf_fast(g.z);
    c[idx]=cn;
    float hv = sigf(g.w)*tanhf_fast(cn);
    f16 h=(f16)hv; hhi[idx]=h; hlo[idx]=(f16)(hv-(float)h);
}

// fused: softmax/argmax + probs + attention (via precomputed V) + dur head + LSTM cell.
// 512 threads; wave-shfl reductions; PARTS-way split-K partial sum inline.
template<int PARTS>
__global__ void k_postapply(const float* __restrict__ rawg, size_t pstride,
                       const float* __restrict__ S, const float* __restrict__ V,
                       const f16* __restrict__ hchi, const f16* __restrict__ hclo,
                       const f16* __restrict__ holdhi, const f16* __restrict__ holdlo,
                       const float* __restrict__ E, const float* __restrict__ wl,
                       const float* __restrict__ biascat,
                       const float* __restrict__ Wdur, const float* __restrict__ bdur,
                       float* __restrict__ outlab, float* __restrict__ outprobs,
                       float* __restrict__ outatt, float* __restrict__ outpad,
                       float* __restrict__ c, f16* __restrict__ hNhi, f16* __restrict__ hNlo,
                       int tstep, int doLstm)
{
    int b=blockIdx.x, t=threadIdx.x;
    int lane=t&63, wv=t>>6;
    __shared__ float aw[3];
    __shared__ float redw[4][8];
    __shared__ int sbest;
    __shared__ float sdv;
    const float* z0 = rawg + (size_t)b*NC;
    // logits softmax/argmax on wave 0
    if (t<64){
        float lgv = -3.0e38f;
        if (t<C){
            float v = 0.f;
            #pragma unroll
            for (int p=0;p<PARTS;p++) v += z0[(size_t)p*pstride + G4H + t];
            lgv = v + biascat[t];
        }
        float m = lgv; int bi = t;
        #pragma unroll
        for (int s2=32;s2>0;s2>>=1){
            float om=__shfl_xor(m,s2); int ob=__shfl_xor(bi,s2);
            if (om>m || (om==m && ob<bi)){ m=om; bi=ob; }
        }
        float e=(t<C)? __expf(lgv-m):0.f;
        float ss=e;
        #pragma unroll
        for (int s2=32;s2>0;s2>>=1) ss+=__shfl_xor(ss,s2);
        if (t<C) outprobs[(size_t)b*(T*C)+tstep*C+t]=e/ss;
        if (t==0){
            sbest=bi;
            outlab[(size_t)tstep*B+b]=(float)bi;
        }
    }
    // attention scores via precomputed V: p_k = h . V[k,b,:]
    float hv_t = (float)hchi[(size_t)b*H + t] + (float)hclo[(size_t)b*H + t];
    float p0 = hv_t * V[((size_t)(0*B+b))*H + t];
    float p1 = hv_t * V[((size_t)(1*B+b))*H + t];
    float p2 = hv_t * V[((size_t)(2*B+b))*H + t];
    #pragma unroll
    for (int s2=32;s2>0;s2>>=1){
        p0 += __shfl_xor(p0,s2); p1 += __shfl_xor(p1,s2); p2 += __shfl_xor(p2,s2);
    }
    if (lane==0){ redw[0][wv]=p0; redw[1][wv]=p1; redw[2][wv]=p2; }
    __syncthreads();
    if (t==0){
        float a0=0.f,a1=0.f,a2=0.f;
        #pragma unroll
        for (int w=0;w<8;w++){ a0+=redw[0][w]; a1+=redw[1][w]; a2+=redw[2][w]; }
        float m=fmaxf(a0,fmaxf(a1,a2));
        float e0=__expf(a0-m), e1=__expf(a1-m), e2=__expf(a2-m);
        float si=1.f/(e0+e1+e2);
        aw[0]=e0*si; aw[1]=e1*si; aw[2]=e2*si;
    }
    __syncthreads();
    float a0=aw[0],a1=aw[1],a2=aw[2];
    const float* S0  = S + (size_t)b*D;
    const float* S1  = S0 + (size_t)B*D;
    const float* S2p = S1 + (size_t)B*D;
    float dp = 0.f;
    float* attp = outatt + (size_t)tstep*B*D + (size_t)b*D;
    {
        int d = t<<1;   // single pass: 512 threads x float2 = 1024 floats = D
        float2 s0 = *(const float2*)(S0+d);
        float2 s1 = *(const float2*)(S1+d);
        float2 s2 = *(const float2*)(S2p+d);
        float2 w2 = *(const float2*)(Wdur+d);
        float2 av;
        av.x = a0*s0.x+a1*s1.x+a2*s2.x;
        av.y = a0*s0.y+a1*s1.y+a2*s2.y;
        *(float2*)(attp+d) = av;
        dp += av.x*w2.x+av.y*w2.y;
    }
    if (holdhi){
        float hvo = (float)holdhi[(size_t)b*H+t] + (float)holdlo[(size_t)b*H+t];
        dp += hvo * Wdur[D+t];
    }
    #pragma unroll
    for (int s2=32;s2>0;s2>>=1) dp += __shfl_xor(dp,s2);
    if (lane==0) redw[3][wv]=dp;
    __syncthreads();
    if (t==0){
        float dv=0.f;
        #pragma unroll
        for (int w=0;w<8;w++) dv+=redw[3][w];
        dv += bdur[0];
        outpad[(size_t)b*(T+1)+tstep+1]=dv; sdv=dv;
    }
    __syncthreads();
    if (doLstm){
        int lb=sbest; float dv=sdv;
        int j=t;   // 512 threads == H
        float4 g4 = *(const float4*)&z0[4*j];
        #pragma unroll
        for (int p=1;p<PARTS;p++){
            float4 h4 = *(const float4*)&z0[(size_t)p*pstride + 4*j];
            g4.x+=h4.x; g4.y+=h4.y; g4.z+=h4.z; g4.w+=h4.w;
        }
        float4 e4 = *(const float4*)&E[(size_t)lb*G4H+4*j];
        float4 w4 = *(const float4*)&wl[4*j];
        float gi = g4.x+e4.x+dv*w4.x;
        float gf = g4.y+e4.y+dv*w4.y;
        float gg = g4.z+e4.z+dv*w4.z;
        float go = g4.w+e4.w+dv*w4.w;
        size_t ci=(size_t)b*H+j;
        float cn = sigf(gf)*c[ci] + sigf(gi)*tanhf_fast(gg);
        c[ci]=cn;
        float hv = sigf(go)*tanhf_fast(cn);
        f16 hh=(f16)hv;
        hNhi[ci]=hh; hNlo[ci]=(f16)(hv-(float)hh);
    }
}

// ================= host =================

extern "C" void kernel_launch(void* const* d_in, const int* in_sizes, int n_in,
                              void* d_out, int out_size, void* d_ws, size_t ws_size,
                              hipStream_t stream) {
    const float* S    = (const float*)d_in[0];
    const float* R    = (const float*)d_in[1];
    const float* clsW = (const float*)d_in[2];
    const float* clsb = (const float*)d_in[3];
    const float* durW = (const float*)d_in[4];
    const float* durb = (const float*)d_in[5];
    const float* linW = (const float*)d_in[6];
    const float* linb = (const float*)d_in[7];
    const float* Wih  = (const float*)d_in[8];
    const float* Whh  = (const float*)d_in[9];
    const float* bih  = (const float*)d_in[10];
    const float* bhh  = (const float*)d_in[11];
    const float* Wp   = (const float*)d_in[12];
    const float* bp   = (const float*)d_in[13];
    const float* Wdur = (const float*)d_in[14];
    const float* bdur = (const float*)d_in[15];
    const float* embed= (const float*)d_in[16];
    const float* Wattn= (const float*)d_in[17];

    float* out = (float*)d_out;
    float* outlab   = out;                 // [T,B]
    float* outprobs = out + 12800;         // [B,T,C]
    float* outca    = out + 627200;        // [B,C]
    float* outpad   = out + 651776;        // [B,T+1]
    float* outatt   = out + 665088;        // [T,B,D]

    float* ws = (float*)d_ws;
    // persistent block
    float* E       = ws + 0;               // 98,304
    float* wl      = ws + 98304;           // 2,048
    float* bias2p  = ws + 100352;          // 2,048
    float* biascat = ws + 102400;          // 64
    float* c       = ws + 102464;          // 262,144
    f16*   hAhi    = (f16*)(ws + 364608);  // 262,144 f16
    f16*   hAlo    = (f16*)(ws + 495680);
    f16*   hBhi    = (f16*)(ws + 626752);
    f16*   hBlo    = (f16*)(ws + 757824);
    f16*   Yhi     = (f16*)(ws + 889920);  // 512*144 f16
    f16*   Ylo     = (f16*)(ws + 926784);
    float* Y       = ws + 963648;          // 73,728 -> ends 1,037,376
    f16*   watthi  = (f16*)(ws + 1037376); // 512*1024 f16 = 262,144 fl
    f16*   wattlo  = (f16*)(ws + 1299520); // ends 1,561,664 < 1,563,712
    f16*   x0hi    = (f16*)(ws + 1563712); // 512*1056 f16
    f16*   x0lo    = (f16*)(ws + 1834048);
    f16*   embhi   = (f16*)(ws + 2104384); // 48*1056 f16
    f16*   emblo   = (f16*)(ws + 2129728);
    // big scratch region, time-multiplexed (within the 40.26 MB floor):
    //  stage1 (x0): linWt hi/lo [SB .. SB+6,858,752) + x0part [SB+6,858,752 ..)
    //  stage2: Wct2 | S hi/lo | V | Wihp (setup) / rawg 2-parts (scan, overlays dead Wihp)
    //          gpart (gx0/E partials) after Wihp.
    const size_t SB = 2155072;
    f16*   lwthi   = (f16*)(ws + SB);               // 1088*6304 f16
    f16*   lwtlo   = (f16*)(ws + SB + 3429376);
    float* x0part  = ws + SB + 6858752;             // ZX0*512*1028 (ws-gated)
    f16*   Wcthi   = (f16*)(ws + SB);               // 2112*512 f16 = 540,672 fl
    f16*   Wctlo   = (f16*)(ws + SB + 540672);      // ends SB+1,081,344
    f16*   Shi     = (f16*)(ws + SB + 1081344);     // 1536*1024 f16 = 786,432 fl
    f16*   Slo     = (f16*)(ws + SB + 1867776);     // ends SB+2,654,208
    float* Vbuf    = ws + SB + 2654208;             // 786,432 fl, ends SB+3,440,640
    f16*   Wihphi  = (f16*)(ws + SB + 3440640);     // 2048*1056 f16 = 1,081,344 fl (setup only)
    f16*   Wihplo  = (f16*)(ws + SB + 4521984);     // ends SB+5,603,328
    float* rawg    = ws + SB + 3440640;             // scan only: 2*512*2112 = 2,162,688 fl (overlays dead Wihp)
    float* gpart   = ws + SB + 5603328;             // setup partials (gx0: 2*512*2048, E: 4*48*2048)

    // ---- workspace-gated split-K config for x0 ----
    int ZX0, ksl_x0;
    if      (ws_size >= (size_t)52898048){ ZX0=8; ksl_x0=800;  }
    else if (ws_size >= (size_t)44476672){ ZX0=4; ksl_x0=1600; }
    else                                 { ZX0=2; ksl_x0=3168; }
    const int ZGX = 2, ksl_gx = 544;
    const int ZE  = 4, ksl_e  = 256;
    const int ZSC = 2, ksl_sc = 256;    // scan split-K: 2 (measured best; 4 regressed r5)

    // ---- setup ----
    k_prep<<<8,256,0,stream>>>(bih,bhh,bp,Wih,bias2p,biascat,wl);
    k_cls<<<K*B,64,0,stream>>>(S,R,clsW,clsb,Y);
    k_curr_action<<<(B*C+255)/256,256,0,stream>>>(Y,outca);
    k_cvtY<<<(B*144+255)/256,256,0,stream>>>(Y,Yhi,Ylo);
    k_dur0<<<B,256,0,stream>>>(R,durW,durb,outpad);
    // linW -> transposed hi/lo [1088][6304]
    k_bt_build<<<dim3((FK+31)/32,(1088+31)/32),256,0,stream>>>(linW,lwthi,lwtlo,6288,1025,1025,1088,FK,1.f);
    // x0 = feat @ linW  (A gathered from Y/S/R, split-K ZX0, z-major XCD swizzle)
    k_mfma<1><<<8*17*ZX0,256,0,stream>>>(nullptr,nullptr,lwthi,lwtlo,x0part,nullptr,
                                         512,1028,FK,0,FK,1028,ksl_x0,(size_t)512*1028,8,ZX0,1,
                                         Yhi,Ylo,S,R);
    k_redcvt<<<(512*KP+255)/256,256,0,stream>>>(x0part,ZX0,(size_t)512*1028,linb,x0hi,x0lo);
    // Wih^T (gate-perm rows) hi/lo   [lwt region is dead from here]
    k_permrows<<<(G4H*KP+255)/256,256,0,stream>>>(Wih,Wihphi,Wihplo,DP1,KP,DP1);
    // gx0 = x0 @ WihT (split-K ZGX, partials in gpart; counted-vmcnt kernel)
    k_mfma0<64><<<8*32*ZGX,256,0,stream>>>(x0hi,x0lo,Wihphi,Wihplo,gpart,nullptr,
                                           512,G4H,KP,KP,KP,G4H,ksl_gx,(size_t)512*G4H,8,ZGX);
    k_lstm0<<<(B*H+255)/256,256,0,stream>>>(gpart,ZGX,(size_t)512*G4H,bias2p,c,hAhi,hAlo);
    k_cvt<<<(48*KP+255)/256,256,0,stream>>>(embed,embhi,emblo,48,1024,1024,KP,1.f);
    // E = embed @ WihT + bias2p (partials reuse gpart after k_lstm0)
    k_mfma0<64><<<1*32*ZE,256,0,stream>>>(embhi,emblo,Wihphi,Wihplo,gpart,nullptr,
                                          48,G4H,KP,KP,KP,G4H,ksl_e,(size_t)48*G4H,1,ZE);
    k_red<<<(48*G4H+255)/256,256,0,stream>>>(E,gpart,ZE,(size_t)48*G4H,48,G4H,G4H,bias2p);
    // V[k,b,:] = (S_k @ Wattn^T)/32  -- removes q (1024 cols) from the step GEMM
    k_cvt<<<(1536*1024+255)/256,256,0,stream>>>(S,Shi,Slo,1536,1024,1024,1024,1.f);
    k_cvt<<<(512*1024+255)/256,256,0,stream>>>(Wattn,watthi,wattlo,512,1024,1024,1024,0.03125f);
    k_mfma0<64><<<24*8,256,0,stream>>>(Shi,Slo,watthi,wattlo,Vbuf,nullptr,
                                       1536,512,1024,1024,1024,512,1024,0,24,1);
    // Wct2 [2112][512]: rows 0..2047 Whh perm | 2048..2095 Wp^T | 2096..2111 pad 0
    k_permrows<<<(G4H*512+255)/256,256,0,stream>>>(Whh,Wcthi,Wctlo,H,H,H);
    k_bt_build<<<dim3(16,2),256,0,stream>>>(Wp,Wcthi+(size_t)2048*512,Wctlo+(size_t)2048*512,
                                            512,48,48,48,512,1.f);
    k_zeroh<<<32,256,0,stream>>>(Wcthi+(size_t)2096*512,Wctlo+(size_t)2096*512,16*512);

    // ---- scan (N-tile 32: 8 x 66 x ZSC = 1056 blocks, ~4/CU) ----
    size_t pstr = (size_t)512*NC;
    f16 *hCurHi=hAhi, *hCurLo=hAlo, *hPrvHi=hBhi, *hPrvLo=hBlo;
    for (int t=0;t<T;t++){
        k_mfma0<32><<<8*66*ZSC,256,0,stream>>>(hCurHi,hCurLo,Wcthi,Wctlo,rawg,nullptr,
                                               512,NCV,H,H,H,NC,ksl_sc,pstr,8,ZSC);
        k_postapply<2><<<B,512,0,stream>>>(rawg,pstr,S,Vbuf,hCurHi,hCurLo,
                                        (t==0)?nullptr:hPrvHi,(t==0)?nullptr:hPrvLo,
                                        E,wl,biascat,Wdur,bdur,
                                        outlab,outprobs,outatt,outpad,
                                        c,hPrvHi,hPrvLo,t,(t<T-1)?1:0);
        f16* th=hPrvHi; hPrvHi=hCurHi; hCurHi=th;
        f16* tl=hPrvLo; hPrvLo=hCurLo; hCurLo=tl;
    }
}